// Round 12
// baseline (144.816 us; speedup 1.0000x reference)
//
#include <hip/hip_runtime.h>
#include <math.h>

// OHNM loss: pos BCE sum + top-k(600000) negative softplus sum, mean over 800000.
//
// R19: kill k_main's compaction machinery. Budget (R13 split): k_main ~60-70us
// vs an 11us HBM floor -- the excess is per-element serial ballot->popc->cur
// chains, 8MB scattered cand writes + zero-fill, per-wave slot bookkeeping.
// The cand array's only purpose was to avoid re-reading x,y in k_B -- but
// x+y (67MB) are L3-RESIDENT (256MB Infinity Cache). So: TWO LEAN PASSES.
//   memset(623KB): ctrl + posp16 + ge256 + 16x1024 L1 partials + h2/h3
//   k_main (2048x256): per element: pos -> softplus into thread-local ps;
//     else k>=K0 -> LDS hist atomic (clamp bin 1023, ge256 flag replaces
//     maxkey). Block end: hist -> partial (blockIdx%16), bred(ps) -> one
//     fp32 atomic into posp16[blockIdx%16] (fp-atomic order nondet already
//     proven benign by R17's h2f/h3f path). NO ballots, NO cand writes.
//   k_B (2048x256): redundant scan1 over 16 partials (64KB; slots GONE) ->
//     b1, r1, tot; hard = (tot<Kneg) || ge256. Stream x,y (L3-hot):
//     y==0 && k>=K0: b>b1 -> ssv += softplus(x) (no key decode -- we have
//     the float); b==b1 -> 4 atomics into h2c/h2f[4096] + h3c/h3f[65536]
//     ((b1,l2,l3) = all 26 fine-key bits -> boundary math exact).
//   k_C (1x1024): h2c->LDS scan2 -> b2; s2 = sum h2f[>b2]; h3 slice of b2;
//     combine -> out. Slow fallback (hard) re-streams x,y coarse -- correct
//     for any input; never taken here. Overflow anomaly class is GONE.

#define K0 0xBF800000u             // f2key(1.0f)
#define FINE_LIMIT 0xC3800000u     // f2key(256.0f)
#define GRID 2048
#define NT 256                     // k_main / k_B threads
#define SELT 1024                  // k_C threads
#define NPART 16                   // L1 partial hists (atomic-merged, pre-zeroed)
#define BBLK 2048                  // k_B blocks (stream x,y at full occupancy)

// ---- ws layout (word offsets) ----
// ctrl: [0]=pos_sum(f32) [1]=tot [2]=ge256 copy [3]=hard [16]=b1 [17]=r1
#define OFF_B1   16
#define OFF_R1   17
#define OFF_POSP16 32                            // 16 split fp32 accumulators
#define OFF_GE256  48                            // >=256 key seen (count)
#define OFF_H1P  64                              // 16 x 1024 L1 partials
#define OFF_H2C  (OFF_H1P + NPART * 1024)        // 16448: 4096 counts
#define OFF_H2F  (OFF_H2C + 4096)                // 20544: 4096 float sums
#define OFF_H3C  (OFF_H2F + 4096)                // 24640: 65536 sub counts
#define OFF_H3F  (OFF_H3C + 65536)               // 90176: 65536 sub float sums
#define OFF_SS   (OFF_H3F + 65536)               // 155712: 2048 sure-sums (f32)
#define ZERO_BYTES (OFF_SS * 4)                  // 622,848 B (SS written-before-read)

__device__ __forceinline__ unsigned f2key(float x) {
    unsigned u = __float_as_uint(x);
    return (u & 0x80000000u) ? ~u : (u | 0x80000000u);
}
__device__ __forceinline__ float key2f(unsigned k) {
    unsigned u = (k & 0x80000000u) ? (k & 0x7FFFFFFFu) : ~k;
    return __uint_as_float(u);
}
__device__ __forceinline__ float softplusf(float x) {
    return fmaxf(x, 0.0f) + __logf(1.0f + __expf(-fabsf(x)));
}
__device__ __forceinline__ float wred(float v) {
    v += __shfl_down(v, 32); v += __shfl_down(v, 16); v += __shfl_down(v, 8);
    v += __shfl_down(v, 4);  v += __shfl_down(v, 2);  v += __shfl_down(v, 1);
    return v;
}
// block float-sum; result valid on thread 0 (256 or 1024 threads)
__device__ float bred(float v) {
    __shared__ float sb[16];
    const int lane = threadIdx.x & 63, w = threadIdx.x >> 6;
    const int nw = blockDim.x >> 6;
    v = wred(v);
    if (lane == 0) sb[w] = v;
    __syncthreads();
    float r = 0.0f;
    if (threadIdx.x == 0) for (int i = 0; i < nw; ++i) r += sb[i];
    __syncthreads();
    return r;
}

// descending rank-select; static (constexpr PER, unrolled -> registers).
// All NTH threads call. First bin (from top) with cum >= R; r = R - above.
// Also returns the grand total of all bins (for the shortfall check).
template<int NTH, int NBINS, int NPARTS>
__device__ void scan_desc(const unsigned* __restrict__ hist, int pstride,
                          unsigned R, unsigned* bin_out, unsigned* r_out,
                          unsigned* tot_out) {
    constexpr int PER = NBINS / NTH;
    __shared__ unsigned sums[NTH];
    __shared__ unsigned res[2];
    const int t = threadIdx.x;
    unsigned local[PER];
    unsigned s = 0;
#pragma unroll
    for (int j = 0; j < PER; ++j) {
        const int bin = NBINS - 1 - (t * PER + j);
        unsigned v = 0;
#pragma unroll
        for (int p = 0; p < NPARTS; ++p) v += hist[p * pstride + bin];
        local[j] = v;
        s += v;
    }
    if (t == 0) { res[0] = 0u; res[1] = 1u; }
    sums[t] = s;
    __syncthreads();
    for (int off = 1; off < NTH; off <<= 1) {
        unsigned v = (t >= off) ? sums[t - off] : 0u;
        __syncthreads();
        sums[t] += v;
        __syncthreads();
    }
    const unsigned total = sums[NTH - 1];
    const unsigned incl = sums[t], excl = incl - s;
    if (excl < R && incl >= R) {
        unsigned cum = excl;
#pragma unroll
        for (int j = 0; j < PER; ++j) {
            if (cum + local[j] >= R) {
                res[0] = (unsigned)(NBINS - 1 - (t * PER + j));
                res[1] = R - cum;
                break;
            }
            cum += local[j];
        }
    }
    __syncthreads();
    *bin_out = res[0];
    *r_out = res[1];
    *tot_out = total;
    __syncthreads();
}

// fine bins: kp = k - K0 (for k in [K0, FINE_LIMIT))
__device__ __forceinline__ unsigned fl1(unsigned kp) { return kp >> 16; }
__device__ __forceinline__ unsigned fl2(unsigned kp) { return (kp >> 4) & 0xFFFu; }
__device__ __forceinline__ unsigned fl3(unsigned kp) { return kp & 0xFu; }
// hard (coarse) bins: full key range
__device__ __forceinline__ unsigned hl1(unsigned k) { return k >> 22; }
__device__ __forceinline__ unsigned hl2(unsigned k) { return (k >> 10) & 0xFFFu; }
__device__ __forceinline__ unsigned hl3(unsigned k) { return k & 0x3FFu; }

// ---- k_main: LEAN pass 1. pos_sum + L1 hist only. No compaction. ----
__global__ __launch_bounds__(NT)
void k_main(const float* __restrict__ x, const float* __restrict__ y,
            unsigned* __restrict__ ws, int n) {
    __shared__ unsigned h[1024];
    const int tid = threadIdx.x;
    for (int i = tid; i < 1024; i += NT) h[i] = 0u;
    __syncthreads();

    float ps = 0.0f;
    unsigned ge = 0u;
    const int n4 = n >> 2;
    const float4* x4 = (const float4*)x;
    const float4* y4 = (const float4*)y;
    const unsigned gtid = blockIdx.x * NT + tid;
    const unsigned gstride = GRID * NT;
    for (unsigned i = gtid; i < (unsigned)n4; i += gstride) {
        float4 xv = x4[i];
        float4 yv = y4[i];
        float xs[4] = {xv.x, xv.y, xv.z, xv.w};
        float ys[4] = {yv.x, yv.y, yv.z, yv.w};
#pragma unroll
        for (int c = 0; c < 4; ++c) {
            if (ys[c] > 0.0f) {
                ps += softplusf(-xs[c]);
            } else {
                unsigned k = f2key(xs[c]);
                if (k >= K0) {
                    unsigned b = (k - K0) >> 16;
                    if (b > 1023u) { b = 1023u; ge = 1u; }
                    atomicAdd(&h[b], 1u);
                }
            }
        }
    }
    // tail (n % 4): scalar, whole grid (no wave-uniformity requirement now)
    for (unsigned i = (unsigned)(n & ~3) + gtid; i < (unsigned)n; i += gstride) {
        float xs = x[i];
        if (y[i] > 0.0f) {
            ps += softplusf(-xs);
        } else {
            unsigned k = f2key(xs);
            if (k >= K0) {
                unsigned b = (k - K0) >> 16;
                if (b > 1023u) { b = 1023u; ge = 1u; }
                atomicAdd(&h[b], 1u);
            }
        }
    }
    // ge256 flag (normally never): one atomic per wave at most
    if (__ballot(ge != 0u) && (tid & 63) == 0)
        atomicAdd(&ws[OFF_GE256], 1u);
    // pos_sum partial -> 16 split fp32 accumulators
    ps = bred(ps);
    if (tid == 0)
        atomicAdd(&((float*)ws)[OFF_POSP16 + (blockIdx.x & 15)], ps);
    // hist -> partial (blockIdx % NPART); only nonzero bins (bred synced us)
    unsigned* part = ws + OFF_H1P + (blockIdx.x & (NPART - 1)) * 1024;
    for (int i = tid; i < 1024; i += NT)
        if (h[i]) atomicAdd(&part[i], h[i]);
}

// ---- k_B: scan1 (redundant, 64KB) + stream x,y (L3-hot): sure-sum + h2/h3 ----
__global__ __launch_bounds__(NT)
void k_B(const float* __restrict__ x, const float* __restrict__ y,
         unsigned* __restrict__ ws, const int* __restrict__ pos_num, int n) {
    const int t = threadIdx.x;
    const unsigned Kneg = (unsigned)(pos_num[0] * 3);

    unsigned b1, r1, tot;
    scan_desc<NT, 1024, NPART>(ws + OFF_H1P, 1024, Kneg, &b1, &r1, &tot);
    const unsigned ge = ws[OFF_GE256];
    const bool hard = (tot < Kneg) || (ge != 0u);
    if (blockIdx.x == 0 && t == 0) {
        float psum = 0.0f;
        for (int i = 0; i < 16; ++i) psum += ((float*)ws)[OFF_POSP16 + i];
        ((float*)ws)[0] = psum;
        ws[1] = tot; ws[2] = ge; ws[3] = hard ? 1u : 0u;
        ws[OFF_B1] = b1; ws[OFF_R1] = r1;
    }
    if (hard) return;                       // k_C takes the slow path

    float ssv = 0.0f;
    const int n4 = n >> 2;
    const float4* x4 = (const float4*)x;
    const float4* y4 = (const float4*)y;
    const unsigned gtid = blockIdx.x * NT + t;
    const unsigned gstride = BBLK * NT;
    for (unsigned i = gtid; i < (unsigned)n4; i += gstride) {
        float4 xv = x4[i];
        float4 yv = y4[i];
        float xs[4] = {xv.x, xv.y, xv.z, xv.w};
        float ys[4] = {yv.x, yv.y, yv.z, yv.w};
#pragma unroll
        for (int c = 0; c < 4; ++c) {
            if (ys[c] != 0.0f) continue;
            unsigned k = f2key(xs[c]);
            if (k < K0) continue;
            unsigned kp = k - K0;
            unsigned b = kp >> 16;
            if (b > b1) ssv += softplusf(xs[c]);
            else if (b == b1) {
                float sp = softplusf(xs[c]);
                unsigned l2 = fl2(kp), l3 = fl3(kp);
                atomicAdd(&ws[OFF_H2C + l2], 1u);
                atomicAdd(&((float*)ws)[OFF_H2F + l2], sp);
                atomicAdd(&ws[OFF_H3C + l2 * 16u + l3], 1u);
                atomicAdd(&((float*)ws)[OFF_H3F + l2 * 16u + l3], sp);
            }
        }
    }
    // tail (n % 4): scalar
    for (unsigned i = (unsigned)(n & ~3) + gtid; i < (unsigned)n; i += gstride) {
        if (y[i] != 0.0f) continue;
        float xv = x[i];
        unsigned k = f2key(xv);
        if (k < K0) continue;
        unsigned kp = k - K0;
        unsigned b = kp >> 16;
        if (b > b1) ssv += softplusf(xv);
        else if (b == b1) {
            float sp = softplusf(xv);
            unsigned l2 = fl2(kp), l3 = fl3(kp);
            atomicAdd(&ws[OFF_H2C + l2], 1u);
            atomicAdd(&((float*)ws)[OFF_H2F + l2], sp);
            atomicAdd(&ws[OFF_H3C + l2 * 16u + l3], 1u);
            atomicAdd(&((float*)ws)[OFF_H3F + l2 * 16u + l3], sp);
        }
    }
    ssv = bred(ssv);
    if (t == 0) ((float*)ws)[OFF_SS + blockIdx.x] = ssv;
}

// ---- correct single-block fallback: coarse 3-level select from x,y ----
// Never taken for the bench input. k_C, SELT threads. ha = 4096-word LDS.
__device__ void slow_select(const float* __restrict__ x, const float* __restrict__ y,
                            unsigned* __restrict__ ws, int n, unsigned Kneg, int pos,
                            float psum, float* __restrict__ out, unsigned* ha) {
    const int t = threadIdx.x;
    __shared__ unsigned bc[2];
    // L1 coarse
    for (int i = t; i < 1024; i += SELT) ha[i] = 0u;
    __syncthreads();
    for (int i = t; i < n; i += SELT)
        if (y[i] == 0.0f) atomicAdd(&ha[hl1(f2key(x[i]))], 1u);
    __syncthreads();
    if (t == 0) {
        unsigned cum = 0, b = 0, r = 1;
        for (int bin = 1023; bin >= 0; --bin) {
            unsigned v = ha[bin];
            if (cum + v >= Kneg) { b = (unsigned)bin; r = Kneg - cum; break; }
            cum += v;
        }
        bc[0] = b; bc[1] = r;
    }
    __syncthreads();
    const unsigned b1 = bc[0], r1 = bc[1];
    __syncthreads();
    // L2
    for (int i = t; i < 4096; i += SELT) ha[i] = 0u;
    __syncthreads();
    float ss = 0.0f;
    for (int i = t; i < n; i += SELT)
        if (y[i] == 0.0f) {
            unsigned k = f2key(x[i]);
            unsigned b = hl1(k);
            if (b > b1) ss += softplusf(key2f(k));
            else if (b == b1) atomicAdd(&ha[hl2(k)], 1u);
        }
    __syncthreads();
    if (t == 0) {
        unsigned cum = 0, b = 0, r = 1;
        for (int bin = 4095; bin >= 0; --bin) {
            unsigned v = ha[bin];
            if (cum + v >= r1) { b = (unsigned)bin; r = r1 - cum; break; }
            cum += v;
        }
        bc[0] = b; bc[1] = r;
    }
    __syncthreads();
    const unsigned b2 = bc[0], r2 = bc[1];
    __syncthreads();
    // L3 (overlay ha[0..2047]; hist data no longer needed)
    unsigned* h3c = ha;
    float* h3f = (float*)(ha + 1024);
    for (int i = t; i < 2048; i += SELT) ha[i] = 0u;
    __syncthreads();
    float s2 = 0.0f;
    for (int i = t; i < n; i += SELT)
        if (y[i] == 0.0f) {
            unsigned k = f2key(x[i]);
            if (hl1(k) == b1) {
                unsigned l2 = hl2(k);
                if (l2 > b2) s2 += softplusf(key2f(k));
                else if (l2 == b2) {
                    atomicAdd(&h3c[hl3(k)], 1u);
                    atomicAdd(&h3f[hl3(k)], softplusf(key2f(k)));
                }
            }
        }
    __syncthreads();
    ss = bred(ss);
    s2 = bred(s2);
    if (t == 0) {
        unsigned cum = 0, c3 = 0, r3 = 1;
        for (int bin = 1023; bin >= 0; --bin) {
            unsigned v = h3c[bin];
            if (cum + v >= r2) { c3 = (unsigned)bin; r3 = r2 - cum; break; }
            cum += v;
        }
        float sf = 0.0f;
        for (int j = (int)c3 + 1; j < 1024; ++j) sf += h3f[j];
        unsigned H = (b1 << 22) | (b2 << 10) | c3;
        out[0] = (psum + ss + s2 + sf + (float)r3 * softplusf(key2f(H)))
                 / (float)(4 * pos);
    }
}

// ---- k_C: scan2 over h2c; s2 from h2f; h3 slice; combine -> out ----
__global__ __launch_bounds__(SELT)
void k_C(const float* __restrict__ x, const float* __restrict__ y,
         unsigned* __restrict__ ws, const int* __restrict__ pos_num,
         int n, float* __restrict__ out) {
    __shared__ unsigned smbuf[4096];   // h2c copy; slow: ha
    __shared__ unsigned h3c_s[16];
    __shared__ float    h3f_s[16];
    const int t = threadIdx.x;
    const int posn = pos_num[0];
    const unsigned Kneg = (unsigned)(posn * 3);
    const float psum = ((float*)ws)[0];
    if (ws[3] != 0u) {                       // hard
        slow_select(x, y, ws, n, Kneg, posn, psum, out, smbuf);
        return;
    }
    const unsigned b1 = ws[OFF_B1], r1 = ws[OFF_R1];
    // h2c -> LDS (16KB coalesced), scan2
    for (int i = t; i < 4096; i += SELT) smbuf[i] = ws[OFF_H2C + i];
    __syncthreads();
    unsigned b2, r2, dummy;
    scan_desc<SELT, 4096, 1>(smbuf, 0, r1, &b2, &r2, &dummy);
    // s2 = sum of h2f over bins > b2 (16KB coalesced)
    float s2v = 0.0f;
    for (unsigned i = (unsigned)t; i < 4096u; i += SELT)
        if (i > b2) s2v += ((float*)ws)[OFF_H2F + i];
    float s2 = bred(s2v);
    // sure-sum total (2048 slots)
    float sse = 0.0f;
    for (int i = t; i < BBLK; i += SELT) sse += ((float*)ws)[OFF_SS + i];
    float ssT = bred(sse);
    // h3 slice of bin b2 -> LDS (parallel read)
    if (t < 16) {
        h3c_s[t] = ws[OFF_H3C + b2 * 16u + (unsigned)t];
        h3f_s[t] = ((float*)ws)[OFF_H3F + b2 * 16u + (unsigned)t];
    }
    __syncthreads();
    if (t == 0) {
        unsigned cum = 0, c3 = 0, r3 = 1;
        for (int bin = 15; bin >= 0; --bin) {
            unsigned v = h3c_s[bin];
            if (cum + v >= r2) { c3 = (unsigned)bin; r3 = r2 - cum; break; }
            cum += v;
        }
        float sf = 0.0f;
        for (int j = (int)c3 + 1; j < 16; ++j) sf += h3f_s[j];
        unsigned H = K0 + ((b1 << 16) | (b2 << 4) | c3);
        out[0] = (psum + ssT + s2 + sf + (float)r3 * softplusf(key2f(H)))
                 / (float)(4 * posn);
    }
}

extern "C" void kernel_launch(void* const* d_in, const int* in_sizes, int n_in,
                              void* d_out, int out_size, void* d_ws, size_t ws_size,
                              hipStream_t stream) {
    const float* x = (const float*)d_in[0];
    const float* y = (const float*)d_in[1];
    const int* pos_num = (const int*)d_in[2];
    float* out = (float*)d_out;
    const int n = in_sizes[0];

    unsigned* ws = (unsigned*)d_ws;
    (void)ws_size;   // footprint now ~631KB, far below provided workspace

    hipMemsetAsync(d_ws, 0, ZERO_BYTES, stream);   // ctrl + partials + h2/h3
    k_main<<<GRID, NT, 0, stream>>>(x, y, ws, n);
    k_B<<<BBLK, NT, 0, stream>>>(x, y, ws, pos_num, n);
    k_C<<<1, SELT, 0, stream>>>(x, y, ws, pos_num, n, out);
}

// Round 13
// 135.192 us; speedup vs baseline: 1.0712x; 1.0712x over previous
//
#include <hip/hip_runtime.h>
#include <math.h>

// OHNM loss: pos BCE sum + top-k(600000) negative softplus sum, mean over 800000.
//
// R20: R17 (126.3us best) with k_B's control cost removed. R19's decisive
// datum: lean k_main (42us) == compaction k_main (~40us) -> the 67MB x,y
// stream itself costs ~40us; compaction is ~free. And k_B's 35-40us was the
// 256-block MLP-starved control reads (96KB slots + 64KB partials/block),
// not the 8MB cand stream. Fixes:
//   * k_main keeps compaction + LDS L1 hist, but per-wave slot arrays are
//     GONE (R19 trick): pos_sum -> 16 split fp32 atomics (order-nondet
//     proven benign R17/R19), maxkey -> GE256 flag at the hist clamp,
//     count -> scan1 total, overflow -> rare OVF flag atomic.
//   * k_B: 1024 blocks; control read = 64KB partials only (L2-cached per
//     XCD, ~67MB aggregate ~ 4us), redundant scan1 -> b1/r1/tot; then the
//     8MB L3-hot cand stream: sure-sum + 4 atomics per b1-key into
//     h2c/h2f[4096] + h3c/h3f[65536] ((b1,l2,l3) = all 26 fine-key bits).
//   * k_C (1x1024): h2c->LDS scan2 -> b2; s2 = sum h2f[>b2]; h3 slice of
//     b2; combine -> out.
// Anomalies (count shortfall / x>=256 / cand overflow) -> hard -> correct
// single-block slow fallback in k_C (never taken for this input).

#define K0 0xBF800000u             // f2key(1.0f)
#define FINE_LIMIT 0xC3800000u     // f2key(256.0f)
#define GRID 2048
#define NT 256                     // k_main / k_B threads
#define SELT 1024                  // k_C threads
#define NWAVES 8192                // GRID x 4 waves
#define REG 256                    // cand words per wave (lambda=159, +7.9 sigma)
#define NPART 16                   // L1 partial hists (atomic-merged, pre-zeroed)
#define BBLK 1024                  // k_B blocks (4/CU)

// ---- ws layout (word offsets) ----
#define OFF_B1   16
#define OFF_R1   17
#define OFF_TOT  18
#define OFF_HARD 19
#define OFF_POSP16 32                            // 16 split fp32 accumulators
#define OFF_OVF  48                              // wave-overflow flag (count)
#define OFF_GE256 49                             // >=256 key seen (count)
#define OFF_H1P  64                              // 16 x 1024 L1 partials
#define OFF_H2C  (OFF_H1P + NPART * 1024)        // 16448: 4096 counts
#define OFF_H2F  (OFF_H2C + 4096)                // 20544: 4096 float sums
#define OFF_H3C  (OFF_H2F + 4096)                // 24640: 65536 sub counts
#define OFF_H3F  (OFF_H3C + 65536)               // 90176: 65536 sub float sums
#define OFF_SS   (OFF_H3F + 65536)               // 155712: 1024 sure-sums (f32)
#define OFF_CAND (OFF_SS + BBLK)                 // 156736 (word%4==0 -> 16B aligned)
#define CANDW    (NWAVES * REG)                  // 2,097,152 words (8 MB)
#define ZERO_BYTES (OFF_SS * 4)                  // 622,848 B (SS written before read)

__device__ __forceinline__ unsigned f2key(float x) {
    unsigned u = __float_as_uint(x);
    return (u & 0x80000000u) ? ~u : (u | 0x80000000u);
}
__device__ __forceinline__ float key2f(unsigned k) {
    unsigned u = (k & 0x80000000u) ? (k & 0x7FFFFFFFu) : ~k;
    return __uint_as_float(u);
}
__device__ __forceinline__ float softplusf(float x) {
    return fmaxf(x, 0.0f) + __logf(1.0f + __expf(-fabsf(x)));
}
__device__ __forceinline__ float wred(float v) {
    v += __shfl_down(v, 32); v += __shfl_down(v, 16); v += __shfl_down(v, 8);
    v += __shfl_down(v, 4);  v += __shfl_down(v, 2);  v += __shfl_down(v, 1);
    return v;
}
// block float-sum; result valid on thread 0 (256 or 1024 threads)
__device__ float bred(float v) {
    __shared__ float sb[16];
    const int lane = threadIdx.x & 63, w = threadIdx.x >> 6;
    const int nw = blockDim.x >> 6;
    v = wred(v);
    if (lane == 0) sb[w] = v;
    __syncthreads();
    float r = 0.0f;
    if (threadIdx.x == 0) for (int i = 0; i < nw; ++i) r += sb[i];
    __syncthreads();
    return r;
}

// descending rank-select; static (constexpr PER, unrolled -> registers).
// All NTH threads call. First bin (from top) with cum >= R; r = R - above.
// Also returns the grand total of all bins.
template<int NTH, int NBINS, int NPARTS>
__device__ void scan_desc(const unsigned* __restrict__ hist, int pstride,
                          unsigned R, unsigned* bin_out, unsigned* r_out,
                          unsigned* tot_out) {
    constexpr int PER = NBINS / NTH;
    __shared__ unsigned sums[NTH];
    __shared__ unsigned res[2];
    const int t = threadIdx.x;
    unsigned local[PER];
    unsigned s = 0;
#pragma unroll
    for (int j = 0; j < PER; ++j) {
        const int bin = NBINS - 1 - (t * PER + j);
        unsigned v = 0;
#pragma unroll
        for (int p = 0; p < NPARTS; ++p) v += hist[p * pstride + bin];
        local[j] = v;
        s += v;
    }
    if (t == 0) { res[0] = 0u; res[1] = 1u; }
    sums[t] = s;
    __syncthreads();
    for (int off = 1; off < NTH; off <<= 1) {
        unsigned v = (t >= off) ? sums[t - off] : 0u;
        __syncthreads();
        sums[t] += v;
        __syncthreads();
    }
    const unsigned total = sums[NTH - 1];
    const unsigned incl = sums[t], excl = incl - s;
    if (excl < R && incl >= R) {
        unsigned cum = excl;
#pragma unroll
        for (int j = 0; j < PER; ++j) {
            if (cum + local[j] >= R) {
                res[0] = (unsigned)(NBINS - 1 - (t * PER + j));
                res[1] = R - cum;
                break;
            }
            cum += local[j];
        }
    }
    __syncthreads();
    *bin_out = res[0];
    *r_out = res[1];
    *tot_out = total;
    __syncthreads();
}

// fine bins: kp = k - K0 (for k in [K0, FINE_LIMIT))
__device__ __forceinline__ unsigned fl1(unsigned kp) { return kp >> 16; }
__device__ __forceinline__ unsigned fl2(unsigned kp) { return (kp >> 4) & 0xFFFu; }
__device__ __forceinline__ unsigned fl3(unsigned kp) { return kp & 0xFu; }
// hard (coarse) bins: full key range
__device__ __forceinline__ unsigned hl1(unsigned k) { return k >> 22; }
__device__ __forceinline__ unsigned hl2(unsigned k) { return (k >> 10) & 0xFFFu; }
__device__ __forceinline__ unsigned hl3(unsigned k) { return k & 0x3FFu; }

// ---- k_main: pos_sum + per-wave compact + L1 hist; NO slot arrays ----
__global__ __launch_bounds__(NT)
void k_main(const float* __restrict__ x, const float* __restrict__ y,
            unsigned* __restrict__ ws, unsigned cap_words, int n) {
    __shared__ unsigned h[1024];
    const int tid = threadIdx.x;
    const int lane = tid & 63;
    const unsigned waveid = blockIdx.x * 4 + (tid >> 6);
    unsigned* cand = ws + OFF_CAND;
    const unsigned base = waveid * REG;
    for (int i = tid; i < 1024; i += NT) h[i] = 0u;
    __syncthreads();

    float ps = 0.0f;
    unsigned ge = 0u, cur = 0u, ovf = 0u;
    const int n4 = n >> 2;
    const float4* x4 = (const float4*)x;
    const float4* y4 = (const float4*)y;
    const unsigned gtid = blockIdx.x * NT + tid;
    const unsigned gstride = GRID * NT;
    for (unsigned i = gtid; i < (unsigned)n4; i += gstride) {
        float4 xv = x4[i];
        float4 yv = y4[i];
        float xs[4] = {xv.x, xv.y, xv.z, xv.w};
        float ys[4] = {yv.x, yv.y, yv.z, yv.w};
#pragma unroll
        for (int c = 0; c < 4; ++c) {
            bool pos = ys[c] > 0.0f;
            if (pos) ps += softplusf(-xs[c]);
            unsigned k = f2key(xs[c]);
            bool cnd = (!pos) && (k >= K0);
            unsigned long long mask = __ballot(cnd);
            if (mask) {
                if (cnd) {
                    unsigned b = (k - K0) >> 16;
                    if (b > 1023u) { b = 1023u; ge = 1u; }
                    atomicAdd(&h[b], 1u);
                    unsigned slot = cur + (unsigned)__popcll(mask & ((1ull << lane) - 1ull));
                    unsigned gi = base + slot;
                    if (slot < REG && gi < cap_words) cand[gi] = k;
                    else ovf = 1u;
                }
                cur += (unsigned)__popcll(mask);
            }
        }
    }
    // tail (n % 4): wave 0, all lanes (keeps cur uniform)
    if (waveid == 0) {
        for (int i = (n & ~3) + lane; i < n; i += 64) {
            float xs = x[i];
            bool pos = y[i] > 0.0f;
            if (pos) ps += softplusf(-xs);
            unsigned k = f2key(xs);
            bool cnd = (!pos) && (k >= K0);
            unsigned long long mask = __ballot(cnd);
            if (mask) {
                if (cnd) {
                    unsigned b = (k - K0) >> 16;
                    if (b > 1023u) { b = 1023u; ge = 1u; }
                    atomicAdd(&h[b], 1u);
                    unsigned slot = cur + (unsigned)__popcll(mask & ((1ull << lane) - 1ull));
                    unsigned gi = base + slot;
                    if (slot < REG && gi < cap_words) cand[gi] = k;
                    else ovf = 1u;
                }
                cur += (unsigned)__popcll(mask);
            }
        }
    }
    // zero-fill padding (k_B skips k < K0; 0 < K0)
    for (unsigned j = cur + lane; j < REG; j += 64) {
        unsigned gi = base + j;
        if (gi < cap_words) cand[gi] = 0u;
    }
    if (base + REG > cap_words) ovf = 1u;     // region didn't fit
    // rare flags: at most one atomic per wave
    unsigned long long movf = __ballot(ovf != 0u);
    unsigned long long mge  = __ballot(ge != 0u);
    if (lane == 0) {
        if (movf) atomicAdd(&ws[OFF_OVF], 1u);
        if (mge)  atomicAdd(&ws[OFF_GE256], 1u);
    }
    // pos_sum partial -> 16 split fp32 accumulators
    ps = bred(ps);
    if (tid == 0)
        atomicAdd(&((float*)ws)[OFF_POSP16 + (blockIdx.x & 15)], ps);
    // merge LDS hist into partial (blockIdx % NPART); only nonzero bins
    unsigned* part = ws + OFF_H1P + (blockIdx.x & (NPART - 1)) * 1024;
    for (int i = tid; i < 1024; i += NT)
        if (h[i]) atomicAdd(&part[i], h[i]);
}

// ---- k_B: redundant scan1 (64KB partials) + 8MB cand stream -> h2/h3 ----
__global__ __launch_bounds__(NT)
void k_B(unsigned* __restrict__ ws, const int* __restrict__ pos_num) {
    const int t = threadIdx.x;
    const unsigned Kneg = (unsigned)(pos_num[0] * 3);

    unsigned b1, r1, tot;
    scan_desc<NT, 1024, NPART>(ws + OFF_H1P, 1024, Kneg, &b1, &r1, &tot);
    const bool hard = (tot < Kneg) || (ws[OFF_GE256] != 0u) || (ws[OFF_OVF] != 0u);
    if (blockIdx.x == 0 && t == 0) {
        ws[OFF_B1] = b1; ws[OFF_R1] = r1; ws[OFF_TOT] = tot;
        ws[OFF_HARD] = hard ? 1u : 0u;
    }
    if (hard) return;                       // k_C takes the slow path

    float ssv = 0.0f;
    const uint4* c4 = (const uint4*)(ws + OFF_CAND);
    for (unsigned i = blockIdx.x * NT + t; i < (unsigned)(CANDW / 4); i += BBLK * NT) {
        uint4 v = c4[i];
        unsigned ks[4] = {v.x, v.y, v.z, v.w};
#pragma unroll
        for (int cc = 0; cc < 4; ++cc) {
            unsigned k = ks[cc];
            if (k < K0) continue;
            unsigned kp = k - K0;
            unsigned b = kp >> 16;
            if (b > b1) ssv += softplusf(key2f(k));
            else if (b == b1) {
                float sp = softplusf(key2f(k));
                unsigned l2 = fl2(kp), l3 = fl3(kp);
                atomicAdd(&ws[OFF_H2C + l2], 1u);
                atomicAdd(&((float*)ws)[OFF_H2F + l2], sp);
                atomicAdd(&ws[OFF_H3C + l2 * 16u + l3], 1u);
                atomicAdd(&((float*)ws)[OFF_H3F + l2 * 16u + l3], sp);
            }
        }
    }
    ssv = bred(ssv);
    if (t == 0) ((float*)ws)[OFF_SS + blockIdx.x] = ssv;
}

// ---- correct single-block fallback: coarse 3-level select from x,y ----
// Never taken for the bench input. k_C, SELT threads. ha = 4096-word LDS.
__device__ void slow_select(const float* __restrict__ x, const float* __restrict__ y,
                            unsigned* __restrict__ ws, int n, unsigned Kneg, int pos,
                            float psum, float* __restrict__ out, unsigned* ha) {
    const int t = threadIdx.x;
    __shared__ unsigned bc[2];
    // L1 coarse
    for (int i = t; i < 1024; i += SELT) ha[i] = 0u;
    __syncthreads();
    for (int i = t; i < n; i += SELT)
        if (y[i] == 0.0f) atomicAdd(&ha[hl1(f2key(x[i]))], 1u);
    __syncthreads();
    if (t == 0) {
        unsigned cum = 0, b = 0, r = 1;
        for (int bin = 1023; bin >= 0; --bin) {
            unsigned v = ha[bin];
            if (cum + v >= Kneg) { b = (unsigned)bin; r = Kneg - cum; break; }
            cum += v;
        }
        bc[0] = b; bc[1] = r;
    }
    __syncthreads();
    const unsigned b1 = bc[0], r1 = bc[1];
    __syncthreads();
    // L2
    for (int i = t; i < 4096; i += SELT) ha[i] = 0u;
    __syncthreads();
    float ss = 0.0f;
    for (int i = t; i < n; i += SELT)
        if (y[i] == 0.0f) {
            unsigned k = f2key(x[i]);
            unsigned b = hl1(k);
            if (b > b1) ss += softplusf(key2f(k));
            else if (b == b1) atomicAdd(&ha[hl2(k)], 1u);
        }
    __syncthreads();
    if (t == 0) {
        unsigned cum = 0, b = 0, r = 1;
        for (int bin = 4095; bin >= 0; --bin) {
            unsigned v = ha[bin];
            if (cum + v >= r1) { b = (unsigned)bin; r = r1 - cum; break; }
            cum += v;
        }
        bc[0] = b; bc[1] = r;
    }
    __syncthreads();
    const unsigned b2 = bc[0], r2 = bc[1];
    __syncthreads();
    // L3 (overlay ha[0..2047]; hist data no longer needed)
    unsigned* h3c = ha;
    float* h3f = (float*)(ha + 1024);
    for (int i = t; i < 2048; i += SELT) ha[i] = 0u;
    __syncthreads();
    float s2 = 0.0f;
    for (int i = t; i < n; i += SELT)
        if (y[i] == 0.0f) {
            unsigned k = f2key(x[i]);
            if (hl1(k) == b1) {
                unsigned l2 = hl2(k);
                if (l2 > b2) s2 += softplusf(key2f(k));
                else if (l2 == b2) {
                    atomicAdd(&h3c[hl3(k)], 1u);
                    atomicAdd(&h3f[hl3(k)], softplusf(key2f(k)));
                }
            }
        }
    __syncthreads();
    ss = bred(ss);
    s2 = bred(s2);
    if (t == 0) {
        unsigned cum = 0, c3 = 0, r3 = 1;
        for (int bin = 1023; bin >= 0; --bin) {
            unsigned v = h3c[bin];
            if (cum + v >= r2) { c3 = (unsigned)bin; r3 = r2 - cum; break; }
            cum += v;
        }
        float sf = 0.0f;
        for (int j = (int)c3 + 1; j < 1024; ++j) sf += h3f[j];
        unsigned H = (b1 << 22) | (b2 << 10) | c3;
        out[0] = (psum + ss + s2 + sf + (float)r3 * softplusf(key2f(H)))
                 / (float)(4 * pos);
    }
}

// ---- k_C: scan2 over h2c; s2 from h2f; h3 slice; combine -> out ----
__global__ __launch_bounds__(SELT)
void k_C(const float* __restrict__ x, const float* __restrict__ y,
         unsigned* __restrict__ ws, const int* __restrict__ pos_num,
         int n, float* __restrict__ out) {
    __shared__ unsigned smbuf[4096];   // h2c copy; slow: ha
    __shared__ unsigned h3c_s[16];
    __shared__ float    h3f_s[16];
    const int t = threadIdx.x;
    const int posn = pos_num[0];
    const unsigned Kneg = (unsigned)(posn * 3);
    float psum = 0.0f;
    for (int i = 0; i < 16; ++i) psum += ((float*)ws)[OFF_POSP16 + i];
    if (ws[OFF_HARD] != 0u) {
        slow_select(x, y, ws, n, Kneg, posn, psum, out, smbuf);
        return;
    }
    const unsigned b1 = ws[OFF_B1], r1 = ws[OFF_R1];
    // h2c -> LDS (16KB coalesced), scan2
    for (int i = t; i < 4096; i += SELT) smbuf[i] = ws[OFF_H2C + i];
    __syncthreads();
    unsigned b2, r2, dummy;
    scan_desc<SELT, 4096, 1>(smbuf, 0, r1, &b2, &r2, &dummy);
    // s2 = sum of h2f over bins > b2 (16KB coalesced)
    float s2v = 0.0f;
    for (unsigned i = (unsigned)t; i < 4096u; i += SELT)
        if (i > b2) s2v += ((float*)ws)[OFF_H2F + i];
    float s2 = bred(s2v);
    // sure-sum total (1024 slots)
    float sse = 0.0f;
    for (int i = t; i < BBLK; i += SELT) sse += ((float*)ws)[OFF_SS + i];
    float ssT = bred(sse);
    // h3 slice of bin b2 -> LDS (parallel read)
    if (t < 16) {
        h3c_s[t] = ws[OFF_H3C + b2 * 16u + (unsigned)t];
        h3f_s[t] = ((float*)ws)[OFF_H3F + b2 * 16u + (unsigned)t];
    }
    __syncthreads();
    if (t == 0) {
        unsigned cum = 0, c3 = 0, r3 = 1;
        for (int bin = 15; bin >= 0; --bin) {
            unsigned v = h3c_s[bin];
            if (cum + v >= r2) { c3 = (unsigned)bin; r3 = r2 - cum; break; }
            cum += v;
        }
        float sf = 0.0f;
        for (int j = (int)c3 + 1; j < 16; ++j) sf += h3f_s[j];
        unsigned H = K0 + ((b1 << 16) | (b2 << 4) | c3);
        out[0] = (psum + ssT + s2 + sf + (float)r3 * softplusf(key2f(H)))
                 / (float)(4 * posn);
    }
}

extern "C" void kernel_launch(void* const* d_in, const int* in_sizes, int n_in,
                              void* d_out, int out_size, void* d_ws, size_t ws_size,
                              hipStream_t stream) {
    const float* x = (const float*)d_in[0];
    const float* y = (const float*)d_in[1];
    const int* pos_num = (const int*)d_in[2];
    float* out = (float*)d_out;
    const int n = in_sizes[0];

    unsigned* ws = (unsigned*)d_ws;
    unsigned cap_words = 0u;
    if (ws_size / 4 > (size_t)OFF_CAND)
        cap_words = (unsigned)(ws_size / 4 - OFF_CAND);
    if (cap_words > (unsigned)CANDW) cap_words = (unsigned)CANDW;

    hipMemsetAsync(d_ws, 0, ZERO_BYTES, stream);   // ctrl + partials + h2/h3
    k_main<<<GRID, NT, 0, stream>>>(x, y, ws, cap_words, n);
    k_B<<<BBLK, NT, 0, stream>>>(ws, pos_num);
    k_C<<<1, SELT, 0, stream>>>(x, y, ws, pos_num, n, out);
}

// Round 14
// 128.686 us; speedup vs baseline: 1.1253x; 1.0506x over previous
//
#include <hip/hip_runtime.h>
#include <math.h>

// OHNM loss: pos BCE sum + top-k(600000) negative softplus sum, mean over 800000.
//
// R21: R17 (126.3us champion) with ONE change: k_main's grid-stride loop is
// software-pipelined depth-2 (issue next iteration's x4/y4 loads before
// processing the current pair). R19/R20 evidence: k_main ~41-45us regardless
// of compaction (lean pass = 42us) -> it is load-LATENCY-bound (VALUBusy 22%,
// HBM 12%, ~1.6TB/s effective): each iteration's branchy ballot+atomic body
// blocks the compiler from pipelining the loads. Manual register prefetch
// breaks that serialization.
// R20 regression diagnosed and reverted: posp16 accumulators shared one
// cache line -> contended-line RMWs (the R4/R6 mistake); per-wave slot
// arrays restored (plain stores, zero contention).
// Structure (unchanged from R17):
//   memset(623KB): ctrl + 16x1024 L1 partials + h2/h3 arrays
//   k_main (2048x256): pos_sum + per-wave cand compact + LDS L1 hist ->
//                      atomic merge into 16 partials  [now pipelined]
//   k_B    (256x256):  slot-reduce (hard/psum, redundant), scan1 -> b1;
//                      ONE cand stream: sure-sum + 4 atomics per b1-key into
//                      h2c/h2f[4096] + h3c/h3f[65536] ((b1,l2,l3) = all 26
//                      fine-key bits -> exact)
//   k_C    (1x1024):   h2c->LDS scan2 -> b2; s2 = sum h2f[>b2]; h3 slice
//                      of b2 -> c3/r3/sf; combine -> out
// Anomalies (count shortfall / x>=256 / cand overflow) -> hard -> correct
// single-block slow fallback in k_C (never taken for this input).

#define K0 0xBF800000u             // f2key(1.0f)
#define FINE_LIMIT 0xC3800000u     // f2key(256.0f)
#define GRID 2048
#define NT 256                     // k_main / k_B threads
#define SELT 1024                  // k_C threads
#define NWAVES 8192                // GRID x 4 waves
#define REG 256                    // cand words per wave (lambda=159, +7.9 sigma)
#define NPART 16                   // L1 partial hists (atomic-merged, pre-zeroed)
#define BBLK 256                   // k_B blocks

// ---- ws layout (word offsets) ----
#define OFF_H1P  64                              // 16 x 1024 L1 partials
#define OFF_H2C  (OFF_H1P + NPART * 1024)        // 16448: 4096 counts
#define OFF_H2F  (OFF_H2C + 4096)                // 20544: 4096 float sums
#define OFF_H3C  (OFF_H2F + 4096)                // 24640: 65536 sub counts
#define OFF_H3F  (OFF_H3C + 65536)               // 90176: 65536 sub float sums
#define OFF_CNT  (OFF_H3F + 65536)               // 155712: per-wave counts
#define OFF_POSP (OFF_CNT + NWAVES)              // per-wave pos partial (f32)
#define OFF_MAXK (OFF_POSP + NWAVES)             // per-wave maxkey
#define OFF_SS   (OFF_MAXK + NWAVES)             // 256 sure-sums (f32)
#define OFF_CAND (OFF_SS + BBLK)                 // 180544 (word%4==0 -> 16B aligned)
#define CANDW    (NWAVES * REG)                  // 2,097,152 words (8 MB)
#define ZERO_BYTES (OFF_CNT * 4)                 // 622,848 B

struct Ctrl { float pos_sum; unsigned cand_count, maxkey, hard; };

__device__ __forceinline__ unsigned f2key(float x) {
    unsigned u = __float_as_uint(x);
    return (u & 0x80000000u) ? ~u : (u | 0x80000000u);
}
__device__ __forceinline__ float key2f(unsigned k) {
    unsigned u = (k & 0x80000000u) ? (k & 0x7FFFFFFFu) : ~k;
    return __uint_as_float(u);
}
__device__ __forceinline__ float softplusf(float x) {
    return fmaxf(x, 0.0f) + __logf(1.0f + __expf(-fabsf(x)));
}
__device__ __forceinline__ float wred(float v) {
    v += __shfl_down(v, 32); v += __shfl_down(v, 16); v += __shfl_down(v, 8);
    v += __shfl_down(v, 4);  v += __shfl_down(v, 2);  v += __shfl_down(v, 1);
    return v;
}
__device__ __forceinline__ unsigned wredmax(unsigned v) {
    v = max(v, (unsigned)__shfl_down((int)v, 32));
    v = max(v, (unsigned)__shfl_down((int)v, 16));
    v = max(v, (unsigned)__shfl_down((int)v, 8));
    v = max(v, (unsigned)__shfl_down((int)v, 4));
    v = max(v, (unsigned)__shfl_down((int)v, 2));
    v = max(v, (unsigned)__shfl_down((int)v, 1));
    return v;
}
// block float-sum; result valid on thread 0 (256 or 1024 threads)
__device__ float bred(float v) {
    __shared__ float sb[16];
    const int lane = threadIdx.x & 63, w = threadIdx.x >> 6;
    const int nw = blockDim.x >> 6;
    v = wred(v);
    if (lane == 0) sb[w] = v;
    __syncthreads();
    float r = 0.0f;
    if (threadIdx.x == 0) for (int i = 0; i < nw; ++i) r += sb[i];
    __syncthreads();
    return r;
}
// block reduce of (sum tot, max mk, or ov, fsum ps); results broadcast to all
__device__ void blockreduce4(unsigned& tot, unsigned& mk, unsigned& ov, float& ps) {
    __shared__ unsigned st[16], sm_[16], so[16];
    __shared__ float sf[16];
    __shared__ unsigned rbu[3];
    __shared__ float rbf;
    const int lane = threadIdx.x & 63, w = threadIdx.x >> 6;
    const int nw = blockDim.x >> 6;
    tot += __shfl_down(tot, 32); tot += __shfl_down(tot, 16); tot += __shfl_down(tot, 8);
    tot += __shfl_down(tot, 4);  tot += __shfl_down(tot, 2);  tot += __shfl_down(tot, 1);
    mk = wredmax(mk);
    ov |= (unsigned)__shfl_down((int)ov, 32); ov |= (unsigned)__shfl_down((int)ov, 16);
    ov |= (unsigned)__shfl_down((int)ov, 8);  ov |= (unsigned)__shfl_down((int)ov, 4);
    ov |= (unsigned)__shfl_down((int)ov, 2);  ov |= (unsigned)__shfl_down((int)ov, 1);
    ps = wred(ps);
    if (lane == 0) { st[w] = tot; sm_[w] = mk; so[w] = ov; sf[w] = ps; }
    __syncthreads();
    if (threadIdx.x == 0) {
        unsigned T = 0, M = 0, O = 0; float P = 0.0f;
        for (int i = 0; i < nw; ++i) { T += st[i]; M = max(M, sm_[i]); O |= so[i]; P += sf[i]; }
        rbu[0] = T; rbu[1] = M; rbu[2] = O; rbf = P;
    }
    __syncthreads();
    tot = rbu[0]; mk = rbu[1]; ov = rbu[2]; ps = rbf;
    __syncthreads();
}

// descending rank-select; static (constexpr PER, unrolled -> registers).
// All NTH threads call. First bin (from top) with cum >= R; r = R - above.
template<int NTH, int NBINS, int NPARTS>
__device__ void scan_desc(const unsigned* __restrict__ hist, int pstride,
                          unsigned R, unsigned* bin_out, unsigned* r_out) {
    constexpr int PER = NBINS / NTH;
    __shared__ unsigned sums[NTH];
    __shared__ unsigned res[2];
    const int t = threadIdx.x;
    unsigned local[PER];
    unsigned s = 0;
#pragma unroll
    for (int j = 0; j < PER; ++j) {
        const int bin = NBINS - 1 - (t * PER + j);
        unsigned v = 0;
#pragma unroll
        for (int p = 0; p < NPARTS; ++p) v += hist[p * pstride + bin];
        local[j] = v;
        s += v;
    }
    if (t == 0) { res[0] = 0u; res[1] = 1u; }
    sums[t] = s;
    __syncthreads();
    for (int off = 1; off < NTH; off <<= 1) {
        unsigned v = (t >= off) ? sums[t - off] : 0u;
        __syncthreads();
        sums[t] += v;
        __syncthreads();
    }
    const unsigned incl = sums[t], excl = incl - s;
    if (excl < R && incl >= R) {
        unsigned cum = excl;
#pragma unroll
        for (int j = 0; j < PER; ++j) {
            if (cum + local[j] >= R) {
                res[0] = (unsigned)(NBINS - 1 - (t * PER + j));
                res[1] = R - cum;
                break;
            }
            cum += local[j];
        }
    }
    __syncthreads();
    *bin_out = res[0];
    *r_out = res[1];
    __syncthreads();
}

// fine bins: kp = k - K0 (for k in [K0, FINE_LIMIT))
__device__ __forceinline__ unsigned fl1(unsigned kp) { return kp >> 16; }
__device__ __forceinline__ unsigned fl2(unsigned kp) { return (kp >> 4) & 0xFFFu; }
__device__ __forceinline__ unsigned fl3(unsigned kp) { return kp & 0xFu; }
// hard (coarse) bins: full key range
__device__ __forceinline__ unsigned hl1(unsigned k) { return k >> 22; }
__device__ __forceinline__ unsigned hl2(unsigned k) { return (k >> 10) & 0xFFFu; }
__device__ __forceinline__ unsigned hl3(unsigned k) { return k & 0x3FFu; }

// process 4 elements (one float4 pair) of the k_main body
#define KMAIN_BODY(xvv, yvv)                                                   \
    {                                                                          \
        float xs_[4] = {(xvv).x, (xvv).y, (xvv).z, (xvv).w};                   \
        float ys_[4] = {(yvv).x, (yvv).y, (yvv).z, (yvv).w};                   \
        _Pragma("unroll")                                                      \
        for (int c_ = 0; c_ < 4; ++c_) {                                       \
            bool pos_ = ys_[c_] > 0.0f;                                        \
            if (pos_) ps += softplusf(-xs_[c_]);                               \
            unsigned k_ = f2key(xs_[c_]);                                      \
            bool cnd_ = (!pos_) && (k_ >= K0);                                 \
            unsigned long long mask_ = __ballot(cnd_);                         \
            if (mask_) {                                                       \
                if (cnd_) {                                                    \
                    kmax = max(kmax, k_);                                      \
                    unsigned b_ = fl1(k_ - K0); if (b_ > 1023u) b_ = 1023u;    \
                    atomicAdd(&h[b_], 1u);                                     \
                    unsigned slot_ = cur +                                     \
                        (unsigned)__popcll(mask_ & ((1ull << lane) - 1ull));   \
                    unsigned gi_ = base + slot_;                               \
                    if (slot_ < REG && gi_ < cap_words) cand[gi_] = k_;        \
                    else ovf = 1u;                                             \
                }                                                              \
                cur += (unsigned)__popcll(mask_);                              \
            }                                                                  \
        }                                                                      \
    }

// ---- k_main: pos_sum + per-wave compact + L1 hist; depth-2 pipelined ----
__global__ __launch_bounds__(NT)
void k_main(const float* __restrict__ x, const float* __restrict__ y,
            unsigned* __restrict__ ws, unsigned cap_words, int n) {
    __shared__ unsigned h[1024];
    const int tid = threadIdx.x;
    const int lane = tid & 63;
    const unsigned waveid = blockIdx.x * 4 + (tid >> 6);
    unsigned* cand = ws + OFF_CAND;
    const unsigned base = waveid * REG;
    for (int i = tid; i < 1024; i += NT) h[i] = 0u;
    __syncthreads();

    float ps = 0.0f;
    unsigned kmax = 0u, cur = 0u, ovf = 0u;
    const unsigned n4 = (unsigned)(n >> 2);
    const float4* x4 = (const float4*)x;
    const float4* y4 = (const float4*)y;
    const unsigned gtid = blockIdx.x * NT + tid;
    const unsigned gstride = GRID * NT;

    // depth-2 software pipeline: issue next loads before processing current
    unsigned i = gtid;
    if (i < n4) {
        float4 xv = x4[i];
        float4 yv = y4[i];
        for (;;) {
            unsigned inext = i + gstride;
            bool more = inext < n4;
            float4 xn, yn;
            if (more) { xn = x4[inext]; yn = y4[inext]; }
            KMAIN_BODY(xv, yv)
            if (!more) break;
            i = inext; xv = xn; yv = yn;
        }
    }
    // tail (n % 4): wave 0, all lanes (keeps cur uniform)
    if (waveid == 0) {
        for (int i2 = (n & ~3) + lane; i2 < n; i2 += 64) {
            float xs = x[i2];
            bool pos = y[i2] > 0.0f;
            if (pos) ps += softplusf(-xs);
            unsigned k = f2key(xs);
            bool cnd = (!pos) && (k >= K0);
            unsigned long long mask = __ballot(cnd);
            if (mask) {
                if (cnd) {
                    kmax = max(kmax, k);
                    unsigned b = fl1(k - K0); if (b > 1023u) b = 1023u;
                    atomicAdd(&h[b], 1u);
                    unsigned slot = cur + (unsigned)__popcll(mask & ((1ull << lane) - 1ull));
                    unsigned gi = base + slot;
                    if (slot < REG && gi < cap_words) cand[gi] = k;
                    else ovf = 1u;
                }
                cur += (unsigned)__popcll(mask);
            }
        }
    }
    // zero-fill padding (k_B skips k < K0; 0 < K0)
    for (unsigned j = cur + lane; j < REG; j += 64) {
        unsigned gi = base + j;
        if (gi < cap_words) cand[gi] = 0u;
    }
    if (base + REG > cap_words) ovf = 1u;     // region didn't fit
    ps = wred(ps);
    kmax = wredmax(kmax);
    unsigned anyovf = (__ballot(ovf != 0u) != 0ull) ? 0x80000000u : 0u;
    if (lane == 0) {
        ws[OFF_CNT + waveid] = (cur & 0x7FFFFFFFu) | anyovf;
        ((float*)ws)[OFF_POSP + waveid] = ps;
        ws[OFF_MAXK + waveid] = kmax;
    }
    // merge LDS hist into partial (blockIdx % NPART); only nonzero bins
    __syncthreads();
    unsigned* part = ws + OFF_H1P + (blockIdx.x & (NPART - 1)) * 1024;
    for (int i2 = tid; i2 < 1024; i2 += NT)
        if (h[i2]) atomicAdd(&part[i2], h[i2]);
}

// ---- k_B: slot-reduce + scan1 + ONE cand stream (sure-sum + h2/h3 atomics) ----
__global__ __launch_bounds__(NT)
void k_B(unsigned* __restrict__ ws, const int* __restrict__ pos_num) {
    const int t = threadIdx.x;
    const unsigned Kneg = (unsigned)(pos_num[0] * 3);

    unsigned tot = 0u, mk = 0u, ov = 0u;
    float psum = 0.0f;
    for (unsigned i = t; i < NWAVES; i += NT) {
        unsigned cc = ws[OFF_CNT + i];
        tot += cc & 0x7FFFFFFFu;
        ov |= cc >> 31;
        mk = max(mk, ws[OFF_MAXK + i]);
        psum += ((float*)ws)[OFF_POSP + i];
    }
    blockreduce4(tot, mk, ov, psum);
    const bool hard = (tot < Kneg) || (mk >= FINE_LIMIT) || (ov != 0u);
    if (blockIdx.x == 0 && t == 0) {
        Ctrl* c = (Ctrl*)ws;
        c->pos_sum = psum; c->cand_count = tot; c->maxkey = mk; c->hard = hard ? 1u : 0u;
    }
    if (hard) return;                       // k_C takes the slow path

    unsigned b1, r1;
    scan_desc<NT, 1024, NPART>(ws + OFF_H1P, 1024, Kneg, &b1, &r1);

    float ssv = 0.0f;
    const uint4* c4 = (const uint4*)(ws + OFF_CAND);
    for (unsigned i = blockIdx.x * NT + t; i < (unsigned)(CANDW / 4); i += BBLK * NT) {
        uint4 v = c4[i];
        unsigned ks[4] = {v.x, v.y, v.z, v.w};
#pragma unroll
        for (int cc = 0; cc < 4; ++cc) {
            unsigned k = ks[cc];
            if (k < K0) continue;
            unsigned kp = k - K0;
            unsigned b = fl1(kp);
            if (b > b1) ssv += softplusf(key2f(k));
            else if (b == b1) {
                float sp = softplusf(key2f(k));
                unsigned l2 = fl2(kp), l3 = fl3(kp);
                atomicAdd(&ws[OFF_H2C + l2], 1u);
                atomicAdd(&((float*)ws)[OFF_H2F + l2], sp);
                atomicAdd(&ws[OFF_H3C + l2 * 16u + l3], 1u);
                atomicAdd(&((float*)ws)[OFF_H3F + l2 * 16u + l3], sp);
            }
        }
    }
    ssv = bred(ssv);
    if (t == 0) ((float*)ws)[OFF_SS + blockIdx.x] = ssv;
    if (blockIdx.x == 0 && t == 0) { ws[16] = b1; ws[17] = r1; }
}

// ---- correct single-block fallback: coarse 3-level select from x,y ----
// Never taken for the bench input. k_C, SELT threads. ha = 4096-word LDS.
__device__ void slow_select(const float* __restrict__ x, const float* __restrict__ y,
                            unsigned* __restrict__ ws, int n, unsigned Kneg, int pos,
                            float psum, float* __restrict__ out, unsigned* ha) {
    const int t = threadIdx.x;
    __shared__ unsigned bc[2];
    // L1 coarse
    for (int i = t; i < 1024; i += SELT) ha[i] = 0u;
    __syncthreads();
    for (int i = t; i < n; i += SELT)
        if (y[i] == 0.0f) atomicAdd(&ha[hl1(f2key(x[i]))], 1u);
    __syncthreads();
    if (t == 0) {
        unsigned cum = 0, b = 0, r = 1;
        for (int bin = 1023; bin >= 0; --bin) {
            unsigned v = ha[bin];
            if (cum + v >= Kneg) { b = (unsigned)bin; r = Kneg - cum; break; }
            cum += v;
        }
        bc[0] = b; bc[1] = r;
    }
    __syncthreads();
    const unsigned b1 = bc[0], r1 = bc[1];
    __syncthreads();
    // L2
    for (int i = t; i < 4096; i += SELT) ha[i] = 0u;
    __syncthreads();
    float ss = 0.0f;
    for (int i = t; i < n; i += SELT)
        if (y[i] == 0.0f) {
            unsigned k = f2key(x[i]);
            unsigned b = hl1(k);
            if (b > b1) ss += softplusf(key2f(k));
            else if (b == b1) atomicAdd(&ha[hl2(k)], 1u);
        }
    __syncthreads();
    if (t == 0) {
        unsigned cum = 0, b = 0, r = 1;
        for (int bin = 4095; bin >= 0; --bin) {
            unsigned v = ha[bin];
            if (cum + v >= r1) { b = (unsigned)bin; r = r1 - cum; break; }
            cum += v;
        }
        bc[0] = b; bc[1] = r;
    }
    __syncthreads();
    const unsigned b2 = bc[0], r2 = bc[1];
    __syncthreads();
    // L3 (overlay ha[0..2047]; hist data no longer needed)
    unsigned* h3c = ha;
    float* h3f = (float*)(ha + 1024);
    for (int i = t; i < 2048; i += SELT) ha[i] = 0u;
    __syncthreads();
    float s2 = 0.0f;
    for (int i = t; i < n; i += SELT)
        if (y[i] == 0.0f) {
            unsigned k = f2key(x[i]);
            if (hl1(k) == b1) {
                unsigned l2 = hl2(k);
                if (l2 > b2) s2 += softplusf(key2f(k));
                else if (l2 == b2) {
                    atomicAdd(&h3c[hl3(k)], 1u);
                    atomicAdd(&h3f[hl3(k)], softplusf(key2f(k)));
                }
            }
        }
    __syncthreads();
    ss = bred(ss);
    s2 = bred(s2);
    if (t == 0) {
        unsigned cum = 0, c3 = 0, r3 = 1;
        for (int bin = 1023; bin >= 0; --bin) {
            unsigned v = h3c[bin];
            if (cum + v >= r2) { c3 = (unsigned)bin; r3 = r2 - cum; break; }
            cum += v;
        }
        float sf = 0.0f;
        for (int j = (int)c3 + 1; j < 1024; ++j) sf += h3f[j];
        unsigned H = (b1 << 22) | (b2 << 10) | c3;
        out[0] = (psum + ss + s2 + sf + (float)r3 * softplusf(key2f(H)))
                 / (float)(4 * pos);
    }
}

// ---- k_C: scan2 over h2c; s2 from h2f; h3 slice; combine -> out ----
__global__ __launch_bounds__(SELT)
void k_C(const float* __restrict__ x, const float* __restrict__ y,
         unsigned* __restrict__ ws, const int* __restrict__ pos_num,
         int n, float* __restrict__ out) {
    __shared__ unsigned smbuf[4096];   // h2c copy; slow: ha
    __shared__ unsigned h3c_s[16];
    __shared__ float    h3f_s[16];
    Ctrl* c = (Ctrl*)ws;
    const int t = threadIdx.x;
    const int posn = pos_num[0];
    const unsigned Kneg = (unsigned)(posn * 3);
    const float psum = c->pos_sum;
    if (c->hard != 0u) {
        slow_select(x, y, ws, n, Kneg, posn, psum, out, smbuf);
        return;
    }
    const unsigned b1 = ws[16], r1 = ws[17];
    // h2c -> LDS (16KB coalesced), scan2
    for (int i = t; i < 4096; i += SELT) smbuf[i] = ws[OFF_H2C + i];
    __syncthreads();
    unsigned b2, r2;
    scan_desc<SELT, 4096, 1>(smbuf, 0, r1, &b2, &r2);
    // s2 = sum of h2f over bins > b2 (16KB coalesced)
    float s2v = 0.0f;
    for (unsigned i = (unsigned)t; i < 4096u; i += SELT)
        if (i > b2) s2v += ((float*)ws)[OFF_H2F + i];
    float s2 = bred(s2v);
    // sure-sum total
    float sse = 0.0f;
    for (int i = t; i < BBLK; i += SELT) sse += ((float*)ws)[OFF_SS + i];
    float ssT = bred(sse);
    // h3 slice of bin b2 -> LDS (parallel read)
    if (t < 16) {
        h3c_s[t] = ws[OFF_H3C + b2 * 16u + (unsigned)t];
        h3f_s[t] = ((float*)ws)[OFF_H3F + b2 * 16u + (unsigned)t];
    }
    __syncthreads();
    if (t == 0) {
        unsigned cum = 0, c3 = 0, r3 = 1;
        for (int bin = 15; bin >= 0; --bin) {
            unsigned v = h3c_s[bin];
            if (cum + v >= r2) { c3 = (unsigned)bin; r3 = r2 - cum; break; }
            cum += v;
        }
        float sf = 0.0f;
        for (int j = (int)c3 + 1; j < 16; ++j) sf += h3f_s[j];
        unsigned H = K0 + ((b1 << 16) | (b2 << 4) | c3);
        out[0] = (psum + ssT + s2 + sf + (float)r3 * softplusf(key2f(H)))
                 / (float)(4 * posn);
    }
}

extern "C" void kernel_launch(void* const* d_in, const int* in_sizes, int n_in,
                              void* d_out, int out_size, void* d_ws, size_t ws_size,
                              hipStream_t stream) {
    const float* x = (const float*)d_in[0];
    const float* y = (const float*)d_in[1];
    const int* pos_num = (const int*)d_in[2];
    float* out = (float*)d_out;
    const int n = in_sizes[0];

    unsigned* ws = (unsigned*)d_ws;
    unsigned cap_words = 0u;
    if (ws_size / 4 > (size_t)OFF_CAND)
        cap_words = (unsigned)(ws_size / 4 - OFF_CAND);
    if (cap_words > (unsigned)CANDW) cap_words = (unsigned)CANDW;

    hipMemsetAsync(d_ws, 0, ZERO_BYTES, stream);   // ctrl + partials + h2/h3
    k_main<<<GRID, NT, 0, stream>>>(x, y, ws, cap_words, n);
    k_B<<<BBLK, NT, 0, stream>>>(ws, pos_num);
    k_C<<<1, SELT, 0, stream>>>(x, y, ws, pos_num, n, out);
}

// Round 15
// 120.949 us; speedup vs baseline: 1.1973x; 1.0640x over previous
//
#include <hip/hip_runtime.h>
#include <math.h>

// OHNM loss: pos BCE sum + top-k(600000) negative softplus sum, mean over 800000.
//
// R22: R17 (126.3us champion) with ONE change: per-wave slot arrays ->
// per-BLOCK slots (2048 x {cnt,posp,maxk}). Evidence: R18 (k_B 8x wider =
// worse) shows k_B is control-READ-bound: each of 256 blocks streams 96KB of
// per-wave slots + 64KB partials at 1-block/CU MLP. Block-level slots shrink
// the slot leg 96KB -> 24KB (4x). k_main epilogue: blockreduce4 + 3 plain
// stores (thread 0), zero contention. pos_sum order changes (block tree) --
// benign per R15/R19/R20. R21's depth-2 pipeline was neutral -> dropped.
// Structure (unchanged):
//   memset(623KB): ctrl + 16x1024 L1 partials + h2/h3 arrays
//   k_main (2048x256): pos_sum + per-wave cand compact (ballot cursors) +
//                      LDS L1 hist -> 16 partials; block-slot epilogue
//   k_B    (256x256):  slot-reduce (2048 slots) + scan1 -> b1; ONE cand
//                      stream: sure-sum + 4 atomics per b1-key into
//                      h2c/h2f[4096] + h3c/h3f[65536] ((b1,l2,l3) = all 26
//                      fine-key bits -> exact)
//   k_C    (1x1024):   h2c->LDS scan2 -> b2; s2 = sum h2f[>b2]; h3 slice
//                      of b2 -> c3/r3/sf; combine -> out
// Anomalies (count shortfall / x>=256 / cand overflow) -> hard -> correct
// single-block slow fallback in k_C (never taken for this input).

#define K0 0xBF800000u             // f2key(1.0f)
#define FINE_LIMIT 0xC3800000u     // f2key(256.0f)
#define GRID 2048
#define NT 256                     // k_main / k_B threads
#define SELT 1024                  // k_C threads
#define REG 256                    // cand words per wave (lambda=159, +7.9 sigma)
#define NPART 16                   // L1 partial hists (atomic-merged, pre-zeroed)
#define BBLK 256                   // k_B blocks

// ---- ws layout (word offsets) ----
#define OFF_H1P  64                              // 16 x 1024 L1 partials
#define OFF_H2C  (OFF_H1P + NPART * 1024)        // 16448: 4096 counts
#define OFF_H2F  (OFF_H2C + 4096)                // 20544: 4096 float sums
#define OFF_H3C  (OFF_H2F + 4096)                // 24640: 65536 sub counts
#define OFF_H3F  (OFF_H3C + 65536)               // 90176: 65536 sub float sums
#define OFF_CNT  (OFF_H3F + 65536)               // 155712: per-BLOCK counts (2048)
#define OFF_POSP (OFF_CNT + GRID)                // 157760: per-block pos partial
#define OFF_MAXK (OFF_POSP + GRID)               // 159808: per-block maxkey
#define OFF_SS   (OFF_MAXK + GRID)               // 161856: 256 sure-sums (f32)
#define OFF_CAND (OFF_SS + BBLK)                 // 162112 (word%4==0 -> 16B aligned)
#define CANDW    (GRID * 4 * REG)                // 2,097,152 words (8 MB)
#define ZERO_BYTES (OFF_CNT * 4)                 // 622,848 B

struct Ctrl { float pos_sum; unsigned cand_count, maxkey, hard; };

__device__ __forceinline__ unsigned f2key(float x) {
    unsigned u = __float_as_uint(x);
    return (u & 0x80000000u) ? ~u : (u | 0x80000000u);
}
__device__ __forceinline__ float key2f(unsigned k) {
    unsigned u = (k & 0x80000000u) ? (k & 0x7FFFFFFFu) : ~k;
    return __uint_as_float(u);
}
__device__ __forceinline__ float softplusf(float x) {
    return fmaxf(x, 0.0f) + __logf(1.0f + __expf(-fabsf(x)));
}
__device__ __forceinline__ float wred(float v) {
    v += __shfl_down(v, 32); v += __shfl_down(v, 16); v += __shfl_down(v, 8);
    v += __shfl_down(v, 4);  v += __shfl_down(v, 2);  v += __shfl_down(v, 1);
    return v;
}
__device__ __forceinline__ unsigned wredmax(unsigned v) {
    v = max(v, (unsigned)__shfl_down((int)v, 32));
    v = max(v, (unsigned)__shfl_down((int)v, 16));
    v = max(v, (unsigned)__shfl_down((int)v, 8));
    v = max(v, (unsigned)__shfl_down((int)v, 4));
    v = max(v, (unsigned)__shfl_down((int)v, 2));
    v = max(v, (unsigned)__shfl_down((int)v, 1));
    return v;
}
// block float-sum; result valid on thread 0 (256 or 1024 threads)
__device__ float bred(float v) {
    __shared__ float sb[16];
    const int lane = threadIdx.x & 63, w = threadIdx.x >> 6;
    const int nw = blockDim.x >> 6;
    v = wred(v);
    if (lane == 0) sb[w] = v;
    __syncthreads();
    float r = 0.0f;
    if (threadIdx.x == 0) for (int i = 0; i < nw; ++i) r += sb[i];
    __syncthreads();
    return r;
}
// block reduce of (sum tot, max mk, or ov, fsum ps); results broadcast to all
__device__ void blockreduce4(unsigned& tot, unsigned& mk, unsigned& ov, float& ps) {
    __shared__ unsigned st[16], sm_[16], so[16];
    __shared__ float sf[16];
    __shared__ unsigned rbu[3];
    __shared__ float rbf;
    const int lane = threadIdx.x & 63, w = threadIdx.x >> 6;
    const int nw = blockDim.x >> 6;
    tot += __shfl_down(tot, 32); tot += __shfl_down(tot, 16); tot += __shfl_down(tot, 8);
    tot += __shfl_down(tot, 4);  tot += __shfl_down(tot, 2);  tot += __shfl_down(tot, 1);
    mk = wredmax(mk);
    ov |= (unsigned)__shfl_down((int)ov, 32); ov |= (unsigned)__shfl_down((int)ov, 16);
    ov |= (unsigned)__shfl_down((int)ov, 8);  ov |= (unsigned)__shfl_down((int)ov, 4);
    ov |= (unsigned)__shfl_down((int)ov, 2);  ov |= (unsigned)__shfl_down((int)ov, 1);
    ps = wred(ps);
    if (lane == 0) { st[w] = tot; sm_[w] = mk; so[w] = ov; sf[w] = ps; }
    __syncthreads();
    if (threadIdx.x == 0) {
        unsigned T = 0, M = 0, O = 0; float P = 0.0f;
        for (int i = 0; i < nw; ++i) { T += st[i]; M = max(M, sm_[i]); O |= so[i]; P += sf[i]; }
        rbu[0] = T; rbu[1] = M; rbu[2] = O; rbf = P;
    }
    __syncthreads();
    tot = rbu[0]; mk = rbu[1]; ov = rbu[2]; ps = rbf;
    __syncthreads();
}

// descending rank-select; static (constexpr PER, unrolled -> registers).
// All NTH threads call. First bin (from top) with cum >= R; r = R - above.
template<int NTH, int NBINS, int NPARTS>
__device__ void scan_desc(const unsigned* __restrict__ hist, int pstride,
                          unsigned R, unsigned* bin_out, unsigned* r_out) {
    constexpr int PER = NBINS / NTH;
    __shared__ unsigned sums[NTH];
    __shared__ unsigned res[2];
    const int t = threadIdx.x;
    unsigned local[PER];
    unsigned s = 0;
#pragma unroll
    for (int j = 0; j < PER; ++j) {
        const int bin = NBINS - 1 - (t * PER + j);
        unsigned v = 0;
#pragma unroll
        for (int p = 0; p < NPARTS; ++p) v += hist[p * pstride + bin];
        local[j] = v;
        s += v;
    }
    if (t == 0) { res[0] = 0u; res[1] = 1u; }
    sums[t] = s;
    __syncthreads();
    for (int off = 1; off < NTH; off <<= 1) {
        unsigned v = (t >= off) ? sums[t - off] : 0u;
        __syncthreads();
        sums[t] += v;
        __syncthreads();
    }
    const unsigned incl = sums[t], excl = incl - s;
    if (excl < R && incl >= R) {
        unsigned cum = excl;
#pragma unroll
        for (int j = 0; j < PER; ++j) {
            if (cum + local[j] >= R) {
                res[0] = (unsigned)(NBINS - 1 - (t * PER + j));
                res[1] = R - cum;
                break;
            }
            cum += local[j];
        }
    }
    __syncthreads();
    *bin_out = res[0];
    *r_out = res[1];
    __syncthreads();
}

// fine bins: kp = k - K0 (for k in [K0, FINE_LIMIT))
__device__ __forceinline__ unsigned fl1(unsigned kp) { return kp >> 16; }
__device__ __forceinline__ unsigned fl2(unsigned kp) { return (kp >> 4) & 0xFFFu; }
__device__ __forceinline__ unsigned fl3(unsigned kp) { return kp & 0xFu; }
// hard (coarse) bins: full key range
__device__ __forceinline__ unsigned hl1(unsigned k) { return k >> 22; }
__device__ __forceinline__ unsigned hl2(unsigned k) { return (k >> 10) & 0xFFFu; }
__device__ __forceinline__ unsigned hl3(unsigned k) { return k & 0x3FFu; }

// ---- k_main: pos_sum + per-wave compact + L1 hist; BLOCK-slot epilogue ----
__global__ __launch_bounds__(NT)
void k_main(const float* __restrict__ x, const float* __restrict__ y,
            unsigned* __restrict__ ws, unsigned cap_words, int n) {
    __shared__ unsigned h[1024];
    const int tid = threadIdx.x;
    const int lane = tid & 63;
    const unsigned waveid = blockIdx.x * 4 + (tid >> 6);
    unsigned* cand = ws + OFF_CAND;
    const unsigned base = waveid * REG;
    for (int i = tid; i < 1024; i += NT) h[i] = 0u;
    __syncthreads();

    float ps = 0.0f;
    unsigned kmax = 0u, cur = 0u, ovf = 0u;
    const int n4 = n >> 2;
    const float4* x4 = (const float4*)x;
    const float4* y4 = (const float4*)y;
    const unsigned gtid = blockIdx.x * NT + tid;
    const unsigned gstride = GRID * NT;
    for (unsigned i = gtid; i < (unsigned)n4; i += gstride) {
        float4 xv = x4[i];
        float4 yv = y4[i];
        float xs[4] = {xv.x, xv.y, xv.z, xv.w};
        float ys[4] = {yv.x, yv.y, yv.z, yv.w};
#pragma unroll
        for (int c = 0; c < 4; ++c) {
            bool pos = ys[c] > 0.0f;
            if (pos) ps += softplusf(-xs[c]);
            unsigned k = f2key(xs[c]);
            bool cnd = (!pos) && (k >= K0);
            unsigned long long mask = __ballot(cnd);
            if (mask) {
                if (cnd) {
                    kmax = max(kmax, k);
                    unsigned b = fl1(k - K0); if (b > 1023u) b = 1023u;
                    atomicAdd(&h[b], 1u);
                    unsigned slot = cur + (unsigned)__popcll(mask & ((1ull << lane) - 1ull));
                    unsigned gi = base + slot;
                    if (slot < REG && gi < cap_words) cand[gi] = k;
                    else ovf = 1u;
                }
                cur += (unsigned)__popcll(mask);
            }
        }
    }
    // tail (n % 4): wave 0, all lanes (keeps cur uniform)
    if (waveid == 0) {
        for (int i = (n & ~3) + lane; i < n; i += 64) {
            float xs = x[i];
            bool pos = y[i] > 0.0f;
            if (pos) ps += softplusf(-xs);
            unsigned k = f2key(xs);
            bool cnd = (!pos) && (k >= K0);
            unsigned long long mask = __ballot(cnd);
            if (mask) {
                if (cnd) {
                    kmax = max(kmax, k);
                    unsigned b = fl1(k - K0); if (b > 1023u) b = 1023u;
                    atomicAdd(&h[b], 1u);
                    unsigned slot = cur + (unsigned)__popcll(mask & ((1ull << lane) - 1ull));
                    unsigned gi = base + slot;
                    if (slot < REG && gi < cap_words) cand[gi] = k;
                    else ovf = 1u;
                }
                cur += (unsigned)__popcll(mask);
            }
        }
    }
    // zero-fill padding (k_B skips k < K0; 0 < K0)
    for (unsigned j = cur + lane; j < REG; j += 64) {
        unsigned gi = base + j;
        if (gi < cap_words) cand[gi] = 0u;
    }
    if (base + REG > cap_words) ovf = 1u;     // region didn't fit

    // ---- block-level slot epilogue (R22): 3 plain stores, no contention ----
    unsigned tin = (lane == 0) ? cur : 0u;    // cur is wave-uniform
    unsigned mkin = kmax;
    unsigned ovin = ovf;
    float psin = ps;
    blockreduce4(tin, mkin, ovin, psin);
    if (tid == 0) {
        ws[OFF_CNT + blockIdx.x] = (tin & 0x7FFFFFFFu) | (ovin ? 0x80000000u : 0u);
        ((float*)ws)[OFF_POSP + blockIdx.x] = psin;
        ws[OFF_MAXK + blockIdx.x] = mkin;
    }
    // merge LDS hist into partial (blockIdx % NPART); only nonzero bins
    unsigned* part = ws + OFF_H1P + (blockIdx.x & (NPART - 1)) * 1024;
    for (int i = tid; i < 1024; i += NT)
        if (h[i]) atomicAdd(&part[i], h[i]);
}

// ---- k_B: slot-reduce (2048 slots) + scan1 + ONE cand stream -> h2/h3 ----
__global__ __launch_bounds__(NT)
void k_B(unsigned* __restrict__ ws, const int* __restrict__ pos_num) {
    const int t = threadIdx.x;
    const unsigned Kneg = (unsigned)(pos_num[0] * 3);

    unsigned tot = 0u, mk = 0u, ov = 0u;
    float psum = 0.0f;
    for (unsigned i = t; i < (unsigned)GRID; i += NT) {
        unsigned cc = ws[OFF_CNT + i];
        tot += cc & 0x7FFFFFFFu;
        ov |= cc >> 31;
        mk = max(mk, ws[OFF_MAXK + i]);
        psum += ((float*)ws)[OFF_POSP + i];
    }
    blockreduce4(tot, mk, ov, psum);
    const bool hard = (tot < Kneg) || (mk >= FINE_LIMIT) || (ov != 0u);
    if (blockIdx.x == 0 && t == 0) {
        Ctrl* c = (Ctrl*)ws;
        c->pos_sum = psum; c->cand_count = tot; c->maxkey = mk; c->hard = hard ? 1u : 0u;
    }
    if (hard) return;                       // k_C takes the slow path

    unsigned b1, r1;
    scan_desc<NT, 1024, NPART>(ws + OFF_H1P, 1024, Kneg, &b1, &r1);

    float ssv = 0.0f;
    const uint4* c4 = (const uint4*)(ws + OFF_CAND);
    for (unsigned i = blockIdx.x * NT + t; i < (unsigned)(CANDW / 4); i += BBLK * NT) {
        uint4 v = c4[i];
        unsigned ks[4] = {v.x, v.y, v.z, v.w};
#pragma unroll
        for (int cc = 0; cc < 4; ++cc) {
            unsigned k = ks[cc];
            if (k < K0) continue;
            unsigned kp = k - K0;
            unsigned b = fl1(kp);
            if (b > b1) ssv += softplusf(key2f(k));
            else if (b == b1) {
                float sp = softplusf(key2f(k));
                unsigned l2 = fl2(kp), l3 = fl3(kp);
                atomicAdd(&ws[OFF_H2C + l2], 1u);
                atomicAdd(&((float*)ws)[OFF_H2F + l2], sp);
                atomicAdd(&ws[OFF_H3C + l2 * 16u + l3], 1u);
                atomicAdd(&((float*)ws)[OFF_H3F + l2 * 16u + l3], sp);
            }
        }
    }
    ssv = bred(ssv);
    if (t == 0) ((float*)ws)[OFF_SS + blockIdx.x] = ssv;
    if (blockIdx.x == 0 && t == 0) { ws[16] = b1; ws[17] = r1; }
}

// ---- correct single-block fallback: coarse 3-level select from x,y ----
// Never taken for the bench input. k_C, SELT threads. ha = 4096-word LDS.
__device__ void slow_select(const float* __restrict__ x, const float* __restrict__ y,
                            unsigned* __restrict__ ws, int n, unsigned Kneg, int pos,
                            float psum, float* __restrict__ out, unsigned* ha) {
    const int t = threadIdx.x;
    __shared__ unsigned bc[2];
    // L1 coarse
    for (int i = t; i < 1024; i += SELT) ha[i] = 0u;
    __syncthreads();
    for (int i = t; i < n; i += SELT)
        if (y[i] == 0.0f) atomicAdd(&ha[hl1(f2key(x[i]))], 1u);
    __syncthreads();
    if (t == 0) {
        unsigned cum = 0, b = 0, r = 1;
        for (int bin = 1023; bin >= 0; --bin) {
            unsigned v = ha[bin];
            if (cum + v >= Kneg) { b = (unsigned)bin; r = Kneg - cum; break; }
            cum += v;
        }
        bc[0] = b; bc[1] = r;
    }
    __syncthreads();
    const unsigned b1 = bc[0], r1 = bc[1];
    __syncthreads();
    // L2
    for (int i = t; i < 4096; i += SELT) ha[i] = 0u;
    __syncthreads();
    float ss = 0.0f;
    for (int i = t; i < n; i += SELT)
        if (y[i] == 0.0f) {
            unsigned k = f2key(x[i]);
            unsigned b = hl1(k);
            if (b > b1) ss += softplusf(key2f(k));
            else if (b == b1) atomicAdd(&ha[hl2(k)], 1u);
        }
    __syncthreads();
    if (t == 0) {
        unsigned cum = 0, b = 0, r = 1;
        for (int bin = 4095; bin >= 0; --bin) {
            unsigned v = ha[bin];
            if (cum + v >= r1) { b = (unsigned)bin; r = r1 - cum; break; }
            cum += v;
        }
        bc[0] = b; bc[1] = r;
    }
    __syncthreads();
    const unsigned b2 = bc[0], r2 = bc[1];
    __syncthreads();
    // L3 (overlay ha[0..2047]; hist data no longer needed)
    unsigned* h3c = ha;
    float* h3f = (float*)(ha + 1024);
    for (int i = t; i < 2048; i += SELT) ha[i] = 0u;
    __syncthreads();
    float s2 = 0.0f;
    for (int i = t; i < n; i += SELT)
        if (y[i] == 0.0f) {
            unsigned k = f2key(x[i]);
            if (hl1(k) == b1) {
                unsigned l2 = hl2(k);
                if (l2 > b2) s2 += softplusf(key2f(k));
                else if (l2 == b2) {
                    atomicAdd(&h3c[hl3(k)], 1u);
                    atomicAdd(&h3f[hl3(k)], softplusf(key2f(k)));
                }
            }
        }
    __syncthreads();
    ss = bred(ss);
    s2 = bred(s2);
    if (t == 0) {
        unsigned cum = 0, c3 = 0, r3 = 1;
        for (int bin = 1023; bin >= 0; --bin) {
            unsigned v = h3c[bin];
            if (cum + v >= r2) { c3 = (unsigned)bin; r3 = r2 - cum; break; }
            cum += v;
        }
        float sf = 0.0f;
        for (int j = (int)c3 + 1; j < 1024; ++j) sf += h3f[j];
        unsigned H = (b1 << 22) | (b2 << 10) | c3;
        out[0] = (psum + ss + s2 + sf + (float)r3 * softplusf(key2f(H)))
                 / (float)(4 * pos);
    }
}

// ---- k_C: scan2 over h2c; s2 from h2f; h3 slice; combine -> out ----
__global__ __launch_bounds__(SELT)
void k_C(const float* __restrict__ x, const float* __restrict__ y,
         unsigned* __restrict__ ws, const int* __restrict__ pos_num,
         int n, float* __restrict__ out) {
    __shared__ unsigned smbuf[4096];   // h2c copy; slow: ha
    __shared__ unsigned h3c_s[16];
    __shared__ float    h3f_s[16];
    Ctrl* c = (Ctrl*)ws;
    const int t = threadIdx.x;
    const int posn = pos_num[0];
    const unsigned Kneg = (unsigned)(posn * 3);
    const float psum = c->pos_sum;
    if (c->hard != 0u) {
        slow_select(x, y, ws, n, Kneg, posn, psum, out, smbuf);
        return;
    }
    const unsigned b1 = ws[16], r1 = ws[17];
    // h2c -> LDS (16KB coalesced), scan2
    for (int i = t; i < 4096; i += SELT) smbuf[i] = ws[OFF_H2C + i];
    __syncthreads();
    unsigned b2, r2;
    scan_desc<SELT, 4096, 1>(smbuf, 0, r1, &b2, &r2);
    // s2 = sum of h2f over bins > b2 (16KB coalesced)
    float s2v = 0.0f;
    for (unsigned i = (unsigned)t; i < 4096u; i += SELT)
        if (i > b2) s2v += ((float*)ws)[OFF_H2F + i];
    float s2 = bred(s2v);
    // sure-sum total
    float sse = 0.0f;
    for (int i = t; i < BBLK; i += SELT) sse += ((float*)ws)[OFF_SS + i];
    float ssT = bred(sse);
    // h3 slice of bin b2 -> LDS (parallel read)
    if (t < 16) {
        h3c_s[t] = ws[OFF_H3C + b2 * 16u + (unsigned)t];
        h3f_s[t] = ((float*)ws)[OFF_H3F + b2 * 16u + (unsigned)t];
    }
    __syncthreads();
    if (t == 0) {
        unsigned cum = 0, c3 = 0, r3 = 1;
        for (int bin = 15; bin >= 0; --bin) {
            unsigned v = h3c_s[bin];
            if (cum + v >= r2) { c3 = (unsigned)bin; r3 = r2 - cum; break; }
            cum += v;
        }
        float sf = 0.0f;
        for (int j = (int)c3 + 1; j < 16; ++j) sf += h3f_s[j];
        unsigned H = K0 + ((b1 << 16) | (b2 << 4) | c3);
        out[0] = (psum + ssT + s2 + sf + (float)r3 * softplusf(key2f(H)))
                 / (float)(4 * posn);
    }
}

extern "C" void kernel_launch(void* const* d_in, const int* in_sizes, int n_in,
                              void* d_out, int out_size, void* d_ws, size_t ws_size,
                              hipStream_t stream) {
    const float* x = (const float*)d_in[0];
    const float* y = (const float*)d_in[1];
    const int* pos_num = (const int*)d_in[2];
    float* out = (float*)d_out;
    const int n = in_sizes[0];

    unsigned* ws = (unsigned*)d_ws;
    unsigned cap_words = 0u;
    if (ws_size / 4 > (size_t)OFF_CAND)
        cap_words = (unsigned)(ws_size / 4 - OFF_CAND);
    if (cap_words > (unsigned)CANDW) cap_words = (unsigned)CANDW;

    hipMemsetAsync(d_ws, 0, ZERO_BYTES, stream);   // ctrl + partials + h2/h3
    k_main<<<GRID, NT, 0, stream>>>(x, y, ws, cap_words, n);
    k_B<<<BBLK, NT, 0, stream>>>(ws, pos_num);
    k_C<<<1, SELT, 0, stream>>>(x, y, ws, pos_num, n, out);
}

// Round 16
// 116.838 us; speedup vs baseline: 1.2395x; 1.0352x over previous
//
#include <hip/hip_runtime.h>
#include <math.h>

// OHNM loss: pos BCE sum + top-k(600000) negative softplus sum, mean over 800000.
//
// R23: R22 (120.9us champion) with two decoupled k_B levers:
//   * NPART 16 -> 8: halves the redundant-scan1 partials read (64->32KB/blk)
//   * BBLK 256 -> 512: doubles cand-stream parallelism. Safe now (R18's 8x
//     widening regression was control x8 = 327MB; here control = 56KB/blk
//     -> 28.7MB total, L2-served).
// Structure (unchanged from R22):
//   memset(590KB): ctrl + 8x1024 L1 partials + h2/h3 arrays
//   k_main (2048x256): pos_sum + per-wave cand compact (ballot cursors) +
//                      LDS L1 hist -> 8 partials; block-slot epilogue
//                      (blockreduce4 + 3 plain stores, zero contention)
//   k_B    (512x256):  slot-reduce (2048 slots) + scan1 -> b1; ONE cand
//                      stream: sure-sum + 4 atomics per b1-key into
//                      h2c/h2f[4096] + h3c/h3f[65536] ((b1,l2,l3) = all 26
//                      fine-key bits -> exact)
//   k_C    (1x1024):   h2c->LDS scan2 -> b2; s2 = sum h2f[>b2]; h3 slice
//                      of b2 -> c3/r3/sf; combine -> out
// Anomalies (count shortfall / x>=256 / cand overflow) -> hard -> correct
// single-block slow fallback in k_C (never taken for this input).

#define K0 0xBF800000u             // f2key(1.0f)
#define FINE_LIMIT 0xC3800000u     // f2key(256.0f)
#define GRID 2048
#define NT 256                     // k_main / k_B threads
#define SELT 1024                  // k_C threads
#define REG 256                    // cand words per wave (lambda=159, +7.9 sigma)
#define NPART 8                    // L1 partial hists (atomic-merged, pre-zeroed)
#define BBLK 512                   // k_B blocks (2/CU)

// ---- ws layout (word offsets) ----
#define OFF_H1P  64                              // 8 x 1024 L1 partials
#define OFF_H2C  (OFF_H1P + NPART * 1024)        // 8256: 4096 counts
#define OFF_H2F  (OFF_H2C + 4096)                // 12352: 4096 float sums
#define OFF_H3C  (OFF_H2F + 4096)                // 16448: 65536 sub counts
#define OFF_H3F  (OFF_H3C + 65536)               // 81984: 65536 sub float sums
#define OFF_CNT  (OFF_H3F + 65536)               // 147520: per-BLOCK counts (2048)
#define OFF_POSP (OFF_CNT + GRID)                // per-block pos partial (f32)
#define OFF_MAXK (OFF_POSP + GRID)               // per-block maxkey
#define OFF_SS   (OFF_MAXK + GRID)               // 512 sure-sums (f32)
#define OFF_CAND (OFF_SS + BBLK)                 // 154176 (word%4==0 -> 16B aligned)
#define CANDW    (GRID * 4 * REG)                // 2,097,152 words (8 MB)
#define ZERO_BYTES (OFF_CNT * 4)                 // 590,080 B

struct Ctrl { float pos_sum; unsigned cand_count, maxkey, hard; };

__device__ __forceinline__ unsigned f2key(float x) {
    unsigned u = __float_as_uint(x);
    return (u & 0x80000000u) ? ~u : (u | 0x80000000u);
}
__device__ __forceinline__ float key2f(unsigned k) {
    unsigned u = (k & 0x80000000u) ? (k & 0x7FFFFFFFu) : ~k;
    return __uint_as_float(u);
}
__device__ __forceinline__ float softplusf(float x) {
    return fmaxf(x, 0.0f) + __logf(1.0f + __expf(-fabsf(x)));
}
__device__ __forceinline__ float wred(float v) {
    v += __shfl_down(v, 32); v += __shfl_down(v, 16); v += __shfl_down(v, 8);
    v += __shfl_down(v, 4);  v += __shfl_down(v, 2);  v += __shfl_down(v, 1);
    return v;
}
__device__ __forceinline__ unsigned wredmax(unsigned v) {
    v = max(v, (unsigned)__shfl_down((int)v, 32));
    v = max(v, (unsigned)__shfl_down((int)v, 16));
    v = max(v, (unsigned)__shfl_down((int)v, 8));
    v = max(v, (unsigned)__shfl_down((int)v, 4));
    v = max(v, (unsigned)__shfl_down((int)v, 2));
    v = max(v, (unsigned)__shfl_down((int)v, 1));
    return v;
}
// block float-sum; result valid on thread 0 (256 or 1024 threads)
__device__ float bred(float v) {
    __shared__ float sb[16];
    const int lane = threadIdx.x & 63, w = threadIdx.x >> 6;
    const int nw = blockDim.x >> 6;
    v = wred(v);
    if (lane == 0) sb[w] = v;
    __syncthreads();
    float r = 0.0f;
    if (threadIdx.x == 0) for (int i = 0; i < nw; ++i) r += sb[i];
    __syncthreads();
    return r;
}
// block reduce of (sum tot, max mk, or ov, fsum ps); results broadcast to all
__device__ void blockreduce4(unsigned& tot, unsigned& mk, unsigned& ov, float& ps) {
    __shared__ unsigned st[16], sm_[16], so[16];
    __shared__ float sf[16];
    __shared__ unsigned rbu[3];
    __shared__ float rbf;
    const int lane = threadIdx.x & 63, w = threadIdx.x >> 6;
    const int nw = blockDim.x >> 6;
    tot += __shfl_down(tot, 32); tot += __shfl_down(tot, 16); tot += __shfl_down(tot, 8);
    tot += __shfl_down(tot, 4);  tot += __shfl_down(tot, 2);  tot += __shfl_down(tot, 1);
    mk = wredmax(mk);
    ov |= (unsigned)__shfl_down((int)ov, 32); ov |= (unsigned)__shfl_down((int)ov, 16);
    ov |= (unsigned)__shfl_down((int)ov, 8);  ov |= (unsigned)__shfl_down((int)ov, 4);
    ov |= (unsigned)__shfl_down((int)ov, 2);  ov |= (unsigned)__shfl_down((int)ov, 1);
    ps = wred(ps);
    if (lane == 0) { st[w] = tot; sm_[w] = mk; so[w] = ov; sf[w] = ps; }
    __syncthreads();
    if (threadIdx.x == 0) {
        unsigned T = 0, M = 0, O = 0; float P = 0.0f;
        for (int i = 0; i < nw; ++i) { T += st[i]; M = max(M, sm_[i]); O |= so[i]; P += sf[i]; }
        rbu[0] = T; rbu[1] = M; rbu[2] = O; rbf = P;
    }
    __syncthreads();
    tot = rbu[0]; mk = rbu[1]; ov = rbu[2]; ps = rbf;
    __syncthreads();
}

// descending rank-select; static (constexpr PER, unrolled -> registers).
// All NTH threads call. First bin (from top) with cum >= R; r = R - above.
template<int NTH, int NBINS, int NPARTS>
__device__ void scan_desc(const unsigned* __restrict__ hist, int pstride,
                          unsigned R, unsigned* bin_out, unsigned* r_out) {
    constexpr int PER = NBINS / NTH;
    __shared__ unsigned sums[NTH];
    __shared__ unsigned res[2];
    const int t = threadIdx.x;
    unsigned local[PER];
    unsigned s = 0;
#pragma unroll
    for (int j = 0; j < PER; ++j) {
        const int bin = NBINS - 1 - (t * PER + j);
        unsigned v = 0;
#pragma unroll
        for (int p = 0; p < NPARTS; ++p) v += hist[p * pstride + bin];
        local[j] = v;
        s += v;
    }
    if (t == 0) { res[0] = 0u; res[1] = 1u; }
    sums[t] = s;
    __syncthreads();
    for (int off = 1; off < NTH; off <<= 1) {
        unsigned v = (t >= off) ? sums[t - off] : 0u;
        __syncthreads();
        sums[t] += v;
        __syncthreads();
    }
    const unsigned incl = sums[t], excl = incl - s;
    if (excl < R && incl >= R) {
        unsigned cum = excl;
#pragma unroll
        for (int j = 0; j < PER; ++j) {
            if (cum + local[j] >= R) {
                res[0] = (unsigned)(NBINS - 1 - (t * PER + j));
                res[1] = R - cum;
                break;
            }
            cum += local[j];
        }
    }
    __syncthreads();
    *bin_out = res[0];
    *r_out = res[1];
    __syncthreads();
}

// fine bins: kp = k - K0 (for k in [K0, FINE_LIMIT))
__device__ __forceinline__ unsigned fl1(unsigned kp) { return kp >> 16; }
__device__ __forceinline__ unsigned fl2(unsigned kp) { return (kp >> 4) & 0xFFFu; }
__device__ __forceinline__ unsigned fl3(unsigned kp) { return kp & 0xFu; }
// hard (coarse) bins: full key range
__device__ __forceinline__ unsigned hl1(unsigned k) { return k >> 22; }
__device__ __forceinline__ unsigned hl2(unsigned k) { return (k >> 10) & 0xFFFu; }
__device__ __forceinline__ unsigned hl3(unsigned k) { return k & 0x3FFu; }

// ---- k_main: pos_sum + per-wave compact + L1 hist; BLOCK-slot epilogue ----
__global__ __launch_bounds__(NT)
void k_main(const float* __restrict__ x, const float* __restrict__ y,
            unsigned* __restrict__ ws, unsigned cap_words, int n) {
    __shared__ unsigned h[1024];
    const int tid = threadIdx.x;
    const int lane = tid & 63;
    const unsigned waveid = blockIdx.x * 4 + (tid >> 6);
    unsigned* cand = ws + OFF_CAND;
    const unsigned base = waveid * REG;
    for (int i = tid; i < 1024; i += NT) h[i] = 0u;
    __syncthreads();

    float ps = 0.0f;
    unsigned kmax = 0u, cur = 0u, ovf = 0u;
    const int n4 = n >> 2;
    const float4* x4 = (const float4*)x;
    const float4* y4 = (const float4*)y;
    const unsigned gtid = blockIdx.x * NT + tid;
    const unsigned gstride = GRID * NT;
    for (unsigned i = gtid; i < (unsigned)n4; i += gstride) {
        float4 xv = x4[i];
        float4 yv = y4[i];
        float xs[4] = {xv.x, xv.y, xv.z, xv.w};
        float ys[4] = {yv.x, yv.y, yv.z, yv.w};
#pragma unroll
        for (int c = 0; c < 4; ++c) {
            bool pos = ys[c] > 0.0f;
            if (pos) ps += softplusf(-xs[c]);
            unsigned k = f2key(xs[c]);
            bool cnd = (!pos) && (k >= K0);
            unsigned long long mask = __ballot(cnd);
            if (mask) {
                if (cnd) {
                    kmax = max(kmax, k);
                    unsigned b = fl1(k - K0); if (b > 1023u) b = 1023u;
                    atomicAdd(&h[b], 1u);
                    unsigned slot = cur + (unsigned)__popcll(mask & ((1ull << lane) - 1ull));
                    unsigned gi = base + slot;
                    if (slot < REG && gi < cap_words) cand[gi] = k;
                    else ovf = 1u;
                }
                cur += (unsigned)__popcll(mask);
            }
        }
    }
    // tail (n % 4): wave 0, all lanes (keeps cur uniform)
    if (waveid == 0) {
        for (int i = (n & ~3) + lane; i < n; i += 64) {
            float xs = x[i];
            bool pos = y[i] > 0.0f;
            if (pos) ps += softplusf(-xs);
            unsigned k = f2key(xs);
            bool cnd = (!pos) && (k >= K0);
            unsigned long long mask = __ballot(cnd);
            if (mask) {
                if (cnd) {
                    kmax = max(kmax, k);
                    unsigned b = fl1(k - K0); if (b > 1023u) b = 1023u;
                    atomicAdd(&h[b], 1u);
                    unsigned slot = cur + (unsigned)__popcll(mask & ((1ull << lane) - 1ull));
                    unsigned gi = base + slot;
                    if (slot < REG && gi < cap_words) cand[gi] = k;
                    else ovf = 1u;
                }
                cur += (unsigned)__popcll(mask);
            }
        }
    }
    // zero-fill padding (k_B skips k < K0; 0 < K0)
    for (unsigned j = cur + lane; j < REG; j += 64) {
        unsigned gi = base + j;
        if (gi < cap_words) cand[gi] = 0u;
    }
    if (base + REG > cap_words) ovf = 1u;     // region didn't fit

    // ---- block-level slot epilogue: 3 plain stores, no contention ----
    unsigned tin = (lane == 0) ? cur : 0u;    // cur is wave-uniform
    unsigned mkin = kmax;
    unsigned ovin = ovf;
    float psin = ps;
    blockreduce4(tin, mkin, ovin, psin);
    if (tid == 0) {
        ws[OFF_CNT + blockIdx.x] = (tin & 0x7FFFFFFFu) | (ovin ? 0x80000000u : 0u);
        ((float*)ws)[OFF_POSP + blockIdx.x] = psin;
        ws[OFF_MAXK + blockIdx.x] = mkin;
    }
    // merge LDS hist into partial (blockIdx % NPART); only nonzero bins
    unsigned* part = ws + OFF_H1P + (blockIdx.x & (NPART - 1)) * 1024;
    for (int i = tid; i < 1024; i += NT)
        if (h[i]) atomicAdd(&part[i], h[i]);
}

// ---- k_B: slot-reduce (2048 slots) + scan1 + ONE cand stream -> h2/h3 ----
__global__ __launch_bounds__(NT)
void k_B(unsigned* __restrict__ ws, const int* __restrict__ pos_num) {
    const int t = threadIdx.x;
    const unsigned Kneg = (unsigned)(pos_num[0] * 3);

    unsigned tot = 0u, mk = 0u, ov = 0u;
    float psum = 0.0f;
    for (unsigned i = t; i < (unsigned)GRID; i += NT) {
        unsigned cc = ws[OFF_CNT + i];
        tot += cc & 0x7FFFFFFFu;
        ov |= cc >> 31;
        mk = max(mk, ws[OFF_MAXK + i]);
        psum += ((float*)ws)[OFF_POSP + i];
    }
    blockreduce4(tot, mk, ov, psum);
    const bool hard = (tot < Kneg) || (mk >= FINE_LIMIT) || (ov != 0u);
    if (blockIdx.x == 0 && t == 0) {
        Ctrl* c = (Ctrl*)ws;
        c->pos_sum = psum; c->cand_count = tot; c->maxkey = mk; c->hard = hard ? 1u : 0u;
    }
    if (hard) return;                       // k_C takes the slow path

    unsigned b1, r1;
    scan_desc<NT, 1024, NPART>(ws + OFF_H1P, 1024, Kneg, &b1, &r1);

    float ssv = 0.0f;
    const uint4* c4 = (const uint4*)(ws + OFF_CAND);
    for (unsigned i = blockIdx.x * NT + t; i < (unsigned)(CANDW / 4); i += BBLK * NT) {
        uint4 v = c4[i];
        unsigned ks[4] = {v.x, v.y, v.z, v.w};
#pragma unroll
        for (int cc = 0; cc < 4; ++cc) {
            unsigned k = ks[cc];
            if (k < K0) continue;
            unsigned kp = k - K0;
            unsigned b = fl1(kp);
            if (b > b1) ssv += softplusf(key2f(k));
            else if (b == b1) {
                float sp = softplusf(key2f(k));
                unsigned l2 = fl2(kp), l3 = fl3(kp);
                atomicAdd(&ws[OFF_H2C + l2], 1u);
                atomicAdd(&((float*)ws)[OFF_H2F + l2], sp);
                atomicAdd(&ws[OFF_H3C + l2 * 16u + l3], 1u);
                atomicAdd(&((float*)ws)[OFF_H3F + l2 * 16u + l3], sp);
            }
        }
    }
    ssv = bred(ssv);
    if (t == 0) ((float*)ws)[OFF_SS + blockIdx.x] = ssv;
    if (blockIdx.x == 0 && t == 0) { ws[16] = b1; ws[17] = r1; }
}

// ---- correct single-block fallback: coarse 3-level select from x,y ----
// Never taken for the bench input. k_C, SELT threads. ha = 4096-word LDS.
__device__ void slow_select(const float* __restrict__ x, const float* __restrict__ y,
                            unsigned* __restrict__ ws, int n, unsigned Kneg, int pos,
                            float psum, float* __restrict__ out, unsigned* ha) {
    const int t = threadIdx.x;
    __shared__ unsigned bc[2];
    // L1 coarse
    for (int i = t; i < 1024; i += SELT) ha[i] = 0u;
    __syncthreads();
    for (int i = t; i < n; i += SELT)
        if (y[i] == 0.0f) atomicAdd(&ha[hl1(f2key(x[i]))], 1u);
    __syncthreads();
    if (t == 0) {
        unsigned cum = 0, b = 0, r = 1;
        for (int bin = 1023; bin >= 0; --bin) {
            unsigned v = ha[bin];
            if (cum + v >= Kneg) { b = (unsigned)bin; r = Kneg - cum; break; }
            cum += v;
        }
        bc[0] = b; bc[1] = r;
    }
    __syncthreads();
    const unsigned b1 = bc[0], r1 = bc[1];
    __syncthreads();
    // L2
    for (int i = t; i < 4096; i += SELT) ha[i] = 0u;
    __syncthreads();
    float ss = 0.0f;
    for (int i = t; i < n; i += SELT)
        if (y[i] == 0.0f) {
            unsigned k = f2key(x[i]);
            unsigned b = hl1(k);
            if (b > b1) ss += softplusf(key2f(k));
            else if (b == b1) atomicAdd(&ha[hl2(k)], 1u);
        }
    __syncthreads();
    if (t == 0) {
        unsigned cum = 0, b = 0, r = 1;
        for (int bin = 4095; bin >= 0; --bin) {
            unsigned v = ha[bin];
            if (cum + v >= r1) { b = (unsigned)bin; r = r1 - cum; break; }
            cum += v;
        }
        bc[0] = b; bc[1] = r;
    }
    __syncthreads();
    const unsigned b2 = bc[0], r2 = bc[1];
    __syncthreads();
    // L3 (overlay ha[0..2047]; hist data no longer needed)
    unsigned* h3c = ha;
    float* h3f = (float*)(ha + 1024);
    for (int i = t; i < 2048; i += SELT) ha[i] = 0u;
    __syncthreads();
    float s2 = 0.0f;
    for (int i = t; i < n; i += SELT)
        if (y[i] == 0.0f) {
            unsigned k = f2key(x[i]);
            if (hl1(k) == b1) {
                unsigned l2 = hl2(k);
                if (l2 > b2) s2 += softplusf(key2f(k));
                else if (l2 == b2) {
                    atomicAdd(&h3c[hl3(k)], 1u);
                    atomicAdd(&h3f[hl3(k)], softplusf(key2f(k)));
                }
            }
        }
    __syncthreads();
    ss = bred(ss);
    s2 = bred(s2);
    if (t == 0) {
        unsigned cum = 0, c3 = 0, r3 = 1;
        for (int bin = 1023; bin >= 0; --bin) {
            unsigned v = h3c[bin];
            if (cum + v >= r2) { c3 = (unsigned)bin; r3 = r2 - cum; break; }
            cum += v;
        }
        float sf = 0.0f;
        for (int j = (int)c3 + 1; j < 1024; ++j) sf += h3f[j];
        unsigned H = (b1 << 22) | (b2 << 10) | c3;
        out[0] = (psum + ss + s2 + sf + (float)r3 * softplusf(key2f(H)))
                 / (float)(4 * pos);
    }
}

// ---- k_C: scan2 over h2c; s2 from h2f; h3 slice; combine -> out ----
__global__ __launch_bounds__(SELT)
void k_C(const float* __restrict__ x, const float* __restrict__ y,
         unsigned* __restrict__ ws, const int* __restrict__ pos_num,
         int n, float* __restrict__ out) {
    __shared__ unsigned smbuf[4096];   // h2c copy; slow: ha
    __shared__ unsigned h3c_s[16];
    __shared__ float    h3f_s[16];
    Ctrl* c = (Ctrl*)ws;
    const int t = threadIdx.x;
    const int posn = pos_num[0];
    const unsigned Kneg = (unsigned)(posn * 3);
    const float psum = c->pos_sum;
    if (c->hard != 0u) {
        slow_select(x, y, ws, n, Kneg, posn, psum, out, smbuf);
        return;
    }
    const unsigned b1 = ws[16], r1 = ws[17];
    // h2c -> LDS (16KB coalesced), scan2
    for (int i = t; i < 4096; i += SELT) smbuf[i] = ws[OFF_H2C + i];
    __syncthreads();
    unsigned b2, r2;
    scan_desc<SELT, 4096, 1>(smbuf, 0, r1, &b2, &r2);
    // s2 = sum of h2f over bins > b2 (16KB coalesced)
    float s2v = 0.0f;
    for (unsigned i = (unsigned)t; i < 4096u; i += SELT)
        if (i > b2) s2v += ((float*)ws)[OFF_H2F + i];
    float s2 = bred(s2v);
    // sure-sum total (512 slots)
    float sse = 0.0f;
    for (int i = t; i < BBLK; i += SELT) sse += ((float*)ws)[OFF_SS + i];
    float ssT = bred(sse);
    // h3 slice of bin b2 -> LDS (parallel read)
    if (t < 16) {
        h3c_s[t] = ws[OFF_H3C + b2 * 16u + (unsigned)t];
        h3f_s[t] = ((float*)ws)[OFF_H3F + b2 * 16u + (unsigned)t];
    }
    __syncthreads();
    if (t == 0) {
        unsigned cum = 0, c3 = 0, r3 = 1;
        for (int bin = 15; bin >= 0; --bin) {
            unsigned v = h3c_s[bin];
            if (cum + v >= r2) { c3 = (unsigned)bin; r3 = r2 - cum; break; }
            cum += v;
        }
        float sf = 0.0f;
        for (int j = (int)c3 + 1; j < 16; ++j) sf += h3f_s[j];
        unsigned H = K0 + ((b1 << 16) | (b2 << 4) | c3);
        out[0] = (psum + ssT + s2 + sf + (float)r3 * softplusf(key2f(H)))
                 / (float)(4 * posn);
    }
}

extern "C" void kernel_launch(void* const* d_in, const int* in_sizes, int n_in,
                              void* d_out, int out_size, void* d_ws, size_t ws_size,
                              hipStream_t stream) {
    const float* x = (const float*)d_in[0];
    const float* y = (const float*)d_in[1];
    const int* pos_num = (const int*)d_in[2];
    float* out = (float*)d_out;
    const int n = in_sizes[0];

    unsigned* ws = (unsigned*)d_ws;
    unsigned cap_words = 0u;
    if (ws_size / 4 > (size_t)OFF_CAND)
        cap_words = (unsigned)(ws_size / 4 - OFF_CAND);
    if (cap_words > (unsigned)CANDW) cap_words = (unsigned)CANDW;

    hipMemsetAsync(d_ws, 0, ZERO_BYTES, stream);   // ctrl + partials + h2/h3
    k_main<<<GRID, NT, 0, stream>>>(x, y, ws, cap_words, n);
    k_B<<<BBLK, NT, 0, stream>>>(ws, pos_num);
    k_C<<<1, SELT, 0, stream>>>(x, y, ws, pos_num, n, out);
}